// Round 8
// baseline (785.608 us; speedup 1.0000x reference)
//
#include <hip/hip_runtime.h>
#include <math.h>

// ---------------------------------------------------------------------------
// LiDARPriorQueryGenerator — MI355X (gfx950). FP32 I/O per reference dtypes.
// wprep2(both weights: bf16 [tap][co][ci] + fp32 [ci][tap][co]) -> smallprep
// (bn-fold, pad-zero, logit-init) -> NHWC bf16 (W padded 130) -> conv1 MFMA
// (single 130-row A tile, dw via ds_read offset) -> featb bf16 -> conv2 MFMA
// + fused 1x1 score -> RADIX-SELECT top>=128 -> EXACT fp32 rescore in THREE
// balanced kernels:
//   rescore_a: grid (cand-quad, b, ci-quarter x co-half) = ~1056 blocks x
//     256 thr (4 waves, round-6's well-scheduled shape). rescore_a is
//     LATENCY-bound (r7 falsified pipe-saturation: duration tracked
//     occupancy exactly at const per-wave throughput). Fix = more resident
//     waves: co-half split halves per-thread work, 4224 waves total,
//     launch_bounds(256,4) keeps VGPR<=128 for 4 waves/SIMD. Each thread:
//     2 co (co0, co0+128), wave = 1 cand, weight dbuf ping-pong.
//   rescore_b: grid (cand-oct, b, cf-quarter) ~272 blocks; sums 4 split-K
//     partials deterministically, BN1+ReLU -> f9 LDS (24KB), conv2 partial
//     over 64 input channels for 8 cands -> acc2 fp32 partials.
//   rescore_c: one wave per cand; sums 4 cf-quarter partials in fixed order,
//     BN2+ReLU, 1x1 score dot, wave-reduce -> exact logits.
// -> final top-100 -> fused FFN/LN/heads/anchor.
// ---------------------------------------------------------------------------

typedef __attribute__((ext_vector_type(8))) short bf16x8;
typedef __attribute__((ext_vector_type(4))) float f32x4;

#define HW 16384
#define WPITCH 130   // padded width: col 0 and 129 are zero pads
#define CCAP 192     // candidate cap (count(key>=K*) typically 128..~132)
#define PSTR 28      // LDS patch stride (floats) per (cand, ci)
// workspace byte offsets
#define WSO_XN    0ULL           // bf16 NHWC padded input; LATER a1part alias
#define WSO_FEATB 34078720ULL    // bf16 NHWC padded feat   (34,078,720)
#define WSO_WP1   68157440ULL    // bf16 [9][256][256] shared_w
#define WSO_WP2   69337088ULL    // bf16 [9][256][256] obj_w1
#define WSO_BNP   70516736ULL    // fp32 scale1,shift1,scale2,shift2,w2f (1280)
#define WSO_LOG   70521856ULL    // fp32 65536 logits
#define WSO_CAND  70784000ULL    // int 4*CCAP
#define WSO_CNT   70787072ULL    // int 4 (+pad)
#define WSO_EXL   70787136ULL    // fp32 4*CCAP
#define WSO_TIDX  70790208ULL    // int 4*100
#define WSO_TLOG  70791808ULL    // fp32 4*100
#define WSO_W1N   70793408ULL    // fp32 [ci][tap][co] shared_w (2,359,296)
#define WSO_W2N   73152704ULL    // fp32 [ci][tap][co] obj_w1   (2,359,296)
#define WSO_A1P   WSO_XN         // fp32 [b][cand][4][9][256] conv1 partials
                                 //   = 28,311,552 B  (xn dead)
#define WSO_ACC2  28311552ULL    // fp32 [b][cand][4][256] conv2 partials
                                 //   = 3,145,728 B; ends 31,457,280 < FEATB

__device__ __forceinline__ float bf2f(short s) {
  return __uint_as_float(((unsigned)(unsigned short)s) << 16);
}
__device__ __forceinline__ short f2bf(float f) {  // RNE
  unsigned u = __float_as_uint(f);
  u += 0x7fffu + ((u >> 16) & 1u);
  return (short)(u >> 16);
}
__device__ __forceinline__ void gll16(const void* g, void* l) {
  __builtin_amdgcn_global_load_lds(
      (const __attribute__((address_space(1))) void*)g,
      (__attribute__((address_space(3))) void*)l, 16, 0, 0);
}

// --- prep: BOTH conv weights in one launch; coalesced read, two writes:
//   wp  bf16 [tap][co][ci]  (MFMA conv)     wn fp32 [ci][tap][co] (rescore)
__global__ void wprep2(const float* __restrict__ s1, const float* __restrict__ s2,
                       short* __restrict__ wp1, short* __restrict__ wp2,
                       float* __restrict__ wn1, float* __restrict__ wn2) {
  int bx = blockIdx.x;  // grid 4608
  const float* src;
  short* wp;
  float* wn;
  if (bx >= 2304) {
    src = s2; wp = wp2; wn = wn2; bx -= 2304;
  } else {
    src = s1; wp = wp1; wn = wn1;
  }
  int i = bx * 256 + threadIdx.x;
  float v = src[i];
  int k = i % 9;
  int r = i / 9;
  int ci = r & 255;
  int co = r >> 8;
  wp[(k * 256 + co) * 256 + ci] = f2bf(v);
  wn[(ci * 9 + k) * 256 + co] = v;
}

// --- prep: padzero (blocks 0..1023) + loginit (1024..1279) + bnfold (1280) --
__global__ void smallprep(const float* g1, const float* b1, const float* m1,
                          const float* v1, const float* g2, const float* b2,
                          const float* m2, const float* v2, const float* w2,
                          const float* ob2, float* __restrict__ bnp,
                          short* __restrict__ xn, short* __restrict__ featb,
                          float* __restrict__ logits) {
  const int blk = blockIdx.x, t = threadIdx.x;
  if (blk < 1024) {
    int i = blk * 256 + t;
    int c = i & 255;
    int r = i >> 8;
    int nh = r >> 1;
    int side = r & 1;
    size_t off = ((size_t)nh * WPITCH + (side ? 129 : 0)) * 256 + c;
    xn[off] = 0;
    featb[off] = 0;
  } else if (blk < 1280) {
    logits[(blk - 1024) * 256 + t] = ob2[0];
  } else {
    float s1 = g1[t] / sqrtf(v1[t] + 1e-5f);
    bnp[t] = s1;
    bnp[256 + t] = b1[t] - m1[t] * s1;
    float s2 = g2[t] / sqrtf(v2[t] + 1e-5f);
    bnp[512 + t] = s2;
    bnp[768 + t] = b2[t] - m2[t] * s2;
    bnp[1024 + t] = w2[t];
  }
}

// --- NCHW f32 -> NHWC bf16 (padded W) ---------------------------------------
__global__ __launch_bounds__(256) void nchw2nhwc(const float* __restrict__ in,
                                                 short* __restrict__ out) {
  __shared__ short tl[64 * 66];
  int n = blockIdx.z, c0 = blockIdx.y * 64, s0 = blockIdx.x * 64;
  int sl = threadIdx.x & 63, cl = threadIdx.x >> 6;
  for (int p = 0; p < 16; ++p) {
    int c = cl + p * 4;
    tl[c * 66 + sl] = f2bf(in[(((size_t)(n * 256 + c0 + c)) << 14) + s0 + sl]);
  }
  __syncthreads();
  int co = threadIdx.x & 63, so = threadIdx.x >> 6;
  for (int p = 0; p < 16; ++p) {
    int S = s0 + so + p * 4;
    int h = S >> 7, w = S & 127;
    out[(((size_t)(n * 128 + h)) * WPITCH + w + 1) * 256 + c0 + co] =
        tl[co * 66 + (so + p * 4)];
  }
}

// --- 3x3 conv + BN + ReLU via MFMA. Single 130-row A tile per (dh,c0)
// window; the dw shift is a ds_read row offset (A staged ONCE, not 3x).
// B: 3 tap tiles. One barrier drain covers 8 gll16 + tail -> 48 MFMA.
template <int OUT_LOGITS>
__global__ __launch_bounds__(256) void conv3x3(const short* __restrict__ inp,
                                               const short* __restrict__ wp,
                                               const float* __restrict__ scale,
                                               const float* __restrict__ shift,
                                               const float* __restrict__ w2f,
                                               short* __restrict__ outb,
                                               float* __restrict__ logits) {
  __shared__ short a_sm[132 * 32];     // rows 0..129 used (130-row tile)
  __shared__ short b_sm[3][128 * 32];
  const int t = threadIdx.x;
  const int wv = t >> 6, lane = t & 63;
  const int l15 = lane & 15, quad = lane >> 4;
  const int tile = blockIdx.x;
  const int img = tile >> 7;
  const int h = tile & 127;
  const int nblk = blockIdx.y;
  const int m0 = (wv & 1) << 6;
  const int n0 = (wv >> 1) << 6;

  f32x4 acc[4][4];
#pragma unroll
  for (int i = 0; i < 4; ++i)
#pragma unroll
    for (int j = 0; j < 4; ++j) {
      acc[i][j][0] = 0.f; acc[i][j][1] = 0.f;
      acc[i][j][2] = 0.f; acc[i][j][3] = 0.f;
    }

  for (int dhi = 0; dhi < 3; ++dhi) {
    const int hy = h + dhi - 1;
    if (hy < 0 || hy > 127) continue;  // block-uniform row-pad skip
    const size_t arow = ((size_t)(img * 128 + hy)) * WPITCH;
    const short* wbase = wp + ((size_t)(dhi * 3 * 256 + nblk * 128)) * 256;

    for (int c0 = 0; c0 < 256; c0 += 32) {
      __syncthreads();
      // stage A: positions [0,128) via 2 gll16 rounds (full-exec)
#pragma unroll
      for (int j = 0; j < 2; ++j) {
        const int seg = (j << 6) + (t >> 2);
        const int cc = t & 3;
        gll16(inp + (arow + seg) * 256 + c0 + cc * 8,
              a_sm + ((size_t)((j << 8) + t)) * 8);
      }
      // positions 128,129: plain dword load + LDS store (exec-mask-safe)
      if (t < 32) {
        const int r = t >> 4, dw = t & 15;
        const int* gsrc = (const int*)(inp + (arow + 128 + r) * 256 + c0) + dw;
        ((int*)a_sm)[(128 + r) * 16 + dw] = *gsrc;
      }
      // stage B: 3 taps of this dh row
#pragma unroll
      for (int dwi = 0; dwi < 3; ++dwi) {
        const short* wtap = wbase + (size_t)dwi * 65536;
#pragma unroll
        for (int j = 0; j < 2; ++j) {
          const int nrow = (j << 6) + (t >> 2);
          const int cc = t & 3;
          gll16(wtap + (size_t)nrow * 256 + c0 + cc * 8,
                b_sm[dwi] + ((size_t)((j << 8) + t)) * 8);
        }
      }
      __syncthreads();  // single drain -> 48 MFMA

#pragma unroll
      for (int dwi = 0; dwi < 3; ++dwi) {
        bf16x8 af[4], bfr[4];
#pragma unroll
        for (int i = 0; i < 4; ++i)
          af[i] = *(const bf16x8*)(a_sm + (dwi + m0 + i * 16 + l15) * 32 + quad * 8);
#pragma unroll
        for (int i = 0; i < 4; ++i)
          bfr[i] = *(const bf16x8*)(b_sm[dwi] + (n0 + i * 16 + l15) * 32 + quad * 8);
#pragma unroll
        for (int i = 0; i < 4; ++i)
#pragma unroll
          for (int j = 0; j < 4; ++j)
            acc[i][j] = __builtin_amdgcn_mfma_f32_16x16x32_bf16(af[i], bfr[j],
                                                                acc[i][j], 0, 0, 0);
      }
    }
  }

  // C/D map: col = lane&15, row = quad*4 + reg
  float sc[4], sh[4], wf[4];
#pragma unroll
  for (int j = 0; j < 4; ++j) {
    const int co = nblk * 128 + n0 + j * 16 + l15;
    sc[j] = scale[co];
    sh[j] = shift[co];
    if (OUT_LOGITS) wf[j] = w2f[co];
  }
  if (OUT_LOGITS) {
    float* lrow = logits + ((size_t)img << 14) + (h << 7);
#pragma unroll
    for (int i = 0; i < 4; ++i) {
#pragma unroll
      for (int r = 0; r < 4; ++r) {
        float part = 0.f;
#pragma unroll
        for (int j = 0; j < 4; ++j) {
          float v = fmaxf(acc[i][j][r] * sc[j] + sh[j], 0.f);
          part += v * wf[j];
        }
        part += __shfl_xor(part, 1);
        part += __shfl_xor(part, 2);
        part += __shfl_xor(part, 4);
        part += __shfl_xor(part, 8);
        if (l15 == 0)
          atomicAdd(&lrow[m0 + i * 16 + quad * 4 + r], part);
      }
    }
  } else {
    const size_t obase = ((size_t)(img * 128 + h)) * WPITCH + 1;
#pragma unroll
    for (int i = 0; i < 4; ++i) {
#pragma unroll
      for (int j = 0; j < 4; ++j) {
        const int co = nblk * 128 + n0 + j * 16 + l15;
#pragma unroll
        for (int r = 0; r < 4; ++r) {
          const int m = m0 + i * 16 + quad * 4 + r;
          float v = fmaxf(acc[i][j][r] * sc[j] + sh[j], 0.f);
          outb[(obase + m) * 256 + co] = f2bf(v);
        }
      }
    }
  }
}

// --- radix-select: all elements with key >= K* (exact rank-128 key) ---------
__global__ __launch_bounds__(1024) void topk_radix(const float* __restrict__ logits,
                                                   int* __restrict__ cand,
                                                   int* __restrict__ cnt_out) {
  __shared__ int hist[2048];
  __shared__ int wsum[16];
  __shared__ unsigned sel_bin;
  __shared__ int sel_above;
  __shared__ int cntr;
  const int b = blockIdx.x, t = threadIdx.x;
  const int lane = t & 63, wid = t >> 6;
  const float* L = logits + (size_t)b * HW;
  const int base = t * 16;
  unsigned kv[16];
#pragma unroll
  for (int i = 0; i < 4; ++i) {
    float4 v = *(const float4*)(L + base + i * 4);
    float f4[4] = {v.x, v.y, v.z, v.w};
#pragma unroll
    for (int j = 0; j < 4; ++j) {
      unsigned u = __float_as_uint(f4[j]);
      kv[i * 4 + j] = u ^ (((unsigned)((int)u >> 31)) | 0x80000000u);
    }
  }
  unsigned prefix = 0, pmask = 0;
  int need = 128;
  const int shifts[3] = {21, 10, 0};
  const int nbs[3] = {2048, 2048, 1024};

  for (int lev = 0; lev < 3; ++lev) {
    const int shift = shifts[lev];
    const int nb = nbs[lev];
    hist[t] = 0;
    hist[t + 1024] = 0;
    __syncthreads();
#pragma unroll
    for (int i = 0; i < 16; ++i)
      if ((kv[i] & pmask) == prefix)
        atomicAdd(&hist[(kv[i] >> shift) & (nb - 1)], 1);
    __syncthreads();
    const int cs = nb >> 10;
    const int bin_hi = nb - 1 - t * cs;
    const int c_hi = hist[bin_hi];
    const int c_lo = (cs == 2) ? hist[bin_hi - 1] : 0;
    const int s = c_hi + c_lo;
    int inc = s;
    for (int off = 1; off < 64; off <<= 1) {
      int nbr = __shfl_up(inc, off);
      if (lane >= off) inc += nbr;
    }
    if (lane == 63) wsum[wid] = inc;
    __syncthreads();
    if (wid == 0) {
      int wv = (lane < 16) ? wsum[lane] : 0;
      for (int off = 1; off < 16; off <<= 1) {
        int nbr = __shfl_up(wv, off);
        if (lane >= off) wv += nbr;
      }
      if (lane < 16) wsum[lane] = wv;
    }
    __syncthreads();
    const int excl = inc - s + (wid ? wsum[wid - 1] : 0);
    if (excl < need && need <= excl + s) {
      if (need <= excl + c_hi) {
        sel_bin = (unsigned)bin_hi;
        sel_above = excl;
      } else {
        sel_bin = (unsigned)(bin_hi - 1);
        sel_above = excl + c_hi;
      }
    }
    __syncthreads();
    prefix |= sel_bin << shift;
    pmask |= ((unsigned)(nb - 1)) << shift;
    need -= sel_above;
    __syncthreads();
  }
  if (t == 0) cntr = 0;
  __syncthreads();
#pragma unroll
  for (int i = 0; i < 16; ++i) {
    if (kv[i] >= prefix) {
      int p = atomicAdd(&cntr, 1);
      if (p < CCAP) cand[b * CCAP + p] = base + i;
    }
  }
  __syncthreads();
  if (t == 0) cnt_out[b] = (cntr < CCAP) ? cntr : CCAP;
}

// --- rescore_a helpers: 18-weight register tile load + one-cand conv step ---
__device__ __forceinline__ void wload2(const float* __restrict__ wr,
                                       float w[2][9]) {
#pragma unroll
  for (int k = 0; k < 9; ++k) {
    w[0][k] = wr[k * 256];
    w[1][k] = wr[k * 256 + 128];
  }
}

__device__ __forceinline__ void conv_step2(const float* __restrict__ pc,
                                           const float w[2][9], float a[2][9]) {
  float xp[28];
  const float4* pr = (const float4*)pc;
#pragma unroll
  for (int q = 0; q < 7; ++q) {
    float4 v = pr[q];
    xp[q * 4 + 0] = v.x; xp[q * 4 + 1] = v.y;
    xp[q * 4 + 2] = v.z; xp[q * 4 + 3] = v.w;
  }
#pragma unroll
  for (int py = 0; py < 3; ++py)
#pragma unroll
    for (int px = 0; px < 3; ++px)
#pragma unroll
      for (int ky = 0; ky < 3; ++ky)
#pragma unroll
        for (int kx = 0; kx < 3; ++kx) {
          const float xv = xp[(py + ky) * 5 + px + kx];
          const int pp = py * 3 + px, kk = ky * 3 + kx;
          a[0][pp] += w[0][kk] * xv;
          a[1][pp] += w[1][kk] * xv;
        }
}

// --- EXACT fp32 rescore, stage A: conv1 partials ----------------------------
// grid (CCAP/4 cand-quads, B, 8 = ci-quarter*2 + co-half), 256 thr (4 waves).
// LATENCY-bound kernel (r7 evidence): lever is resident waves. co-half split
// halves per-thread work -> ~1056 blocks, 4224 waves (~16.5/CU resident).
// Thread map: col = t&63, co0 = hf*64+col; thread computes co0 and co0+128;
// wave g = t>>6 owns one cand (patch reads wave-uniform broadcast). Weight
// dbuf ping-pong. Per-(cand,quarter,co) accumulation order unchanged
// (ci ascending, same tap nest) -> bit-identical output.
__global__ __launch_bounds__(256, 4) void rescore_a(
    const float* __restrict__ bev, const float* __restrict__ w1n,
    const int* __restrict__ cand, const int* __restrict__ cnt,
    float* __restrict__ a1part) {
  const int bx = blockIdx.x, b = blockIdx.y, z = blockIdx.z;
  const int q = z >> 1, hf = z & 1;    // ci-quarter, co-half
  const int t = threadIdx.x;
  const int n = cnt[b];
  const int c0 = bx * 4;
  if (c0 >= n) return;                 // block-uniform
  const int nc = (n - c0 < 4) ? (n - c0) : 4;
  const int ci0 = q << 6;
  __shared__ float patch[4 * 64 * PSTR];  // 28,672 B

  // stage zero-padded 5x5 patches for this ci-quarter, up to 4 candidates
  {
    const int TE = nc * 1600;
    int sg[4];
#pragma unroll
    for (int g = 0; g < 4; ++g) {
      int cc = c0 + g;
      sg[g] = cand[b * CCAP + ((cc < n) ? cc : (n - 1))];
    }
#pragma unroll
    for (int k = 0; k < 25; ++k) {
      int e = t + (k << 8);
      if (e < TE) {
        int g = (e >= 3200) ? ((e >= 4800) ? 3 : 2) : ((e >= 1600) ? 1 : 0);
        int rem = e - g * 1600;
        int ci = rem / 25;
        int rj = rem - ci * 25;
        int r = rj / 5;
        int j = rj - r * 5;
        int s = sg[g];
        int hy = (s >> 7) - 2 + r, wx = (s & 127) - 2 + j;
        float v = 0.f;
        if (hy >= 0 && hy < 128 && wx >= 0 && wx < 128)
          v = bev[(((size_t)(b * 256 + ci0 + ci)) << 14) + (hy << 7) + wx];
        patch[(g * 64 + ci) * PSTR + rj] = v;
      } else {
        // keep LDS defined for inactive slots (reads happen, writes skipped)
        int g2z = (e >= 3200) ? ((e >= 4800) ? 3 : 2) : 1;
        int rem = e - g2z * 1600;
        int ci = rem / 25;
        int rj = rem - ci * 25;
        patch[(g2z * 64 + ci) * PSTR + rj] = 0.f;
      }
    }
  }
  __syncthreads();

  const int col = t & 63;
  const int g = t >> 6;                // wave-uniform candidate index
  const int co0 = (hf << 6) + col;     // thread computes co0 and co0+128
  float a[2][9];
#pragma unroll
  for (int h = 0; h < 2; ++h)
#pragma unroll
    for (int p = 0; p < 9; ++p) a[h][p] = 0.f;

  const float* pbase = patch + (g << 6) * PSTR;
  const float* wbase = w1n + (size_t)ci0 * 2304 + co0;

  float wA[2][9], wB[2][9];
  wload2(wbase, wA);                     // ci = 0
  for (int ci = 0; ci < 64; ci += 2) {
    wload2(wbase + (size_t)(ci + 1) * 2304, wB);   // prefetch ci+1
    conv_step2(pbase + ci * PSTR, wA, a);
    if (ci + 2 < 64)
      wload2(wbase + (size_t)(ci + 2) * 2304, wA); // prefetch ci+2
    conv_step2(pbase + (ci + 1) * PSTR, wB, a);
  }

  if (g < nc) {                          // wave-uniform
    const int c = c0 + g;
    float* dst =
        a1part + ((((size_t)(b * CCAP + c) * 4 + q) * 9) << 8) + co0;
#pragma unroll
    for (int p = 0; p < 9; ++p) {
      dst[p << 8] = a[0][p];
      dst[(p << 8) + 128] = a[1][p];
    }
  }
}

// --- EXACT fp32 rescore, stage B: BN1+ReLU -> conv2 cf-quarter partials -----
// grid (CCAP/8, B, 4 cf-quarters), 256 thr, 24KB LDS. 8 candidates share one
// 0.59MB w2n-quarter stream; each block sums the 4 ci-split conv1 partials
// (fixed order), BN1+ReLU into f9, then conv2 partial over its 64 input
// channels -> acc2[b][cand][z][co].
__global__ __launch_bounds__(256) void rescore_b(const float* __restrict__ a1part,
                                                 const float* __restrict__ w2n,
                                                 const float* __restrict__ bnp,
                                                 const int* __restrict__ cnt,
                                                 float* __restrict__ acc2) {
  const int bx = blockIdx.x, b = blockIdx.y, z = blockIdx.z;
  const int t = threadIdx.x;
  const int n = cnt[b];
  const int cbase = bx * 8;
  if (cbase >= n) return;              // block-uniform
  const int zb = z << 6;
  __shared__ float f9[8 * 64 * 12];    // 24,576 B

  const int cf = t & 63;               // local feature channel
  const int pg = t >> 6;               // wave-uniform p-group
  const int cfg = zb + cf;
  const float sc1 = bnp[cfg], sh1 = bnp[256 + cfg];
#pragma unroll
  for (int g = 0; g < 8; ++g) {
    const int c = cbase + g;
    if (c < n) {                       // block-uniform per g
      const float* src =
          a1part + ((((size_t)(b * CCAP + c)) * 36) << 8) + cfg;
      for (int p = pg; p < 9; p += 4) {
        float v = src[(size_t)(0 * 9 + p) << 8] + src[(size_t)(1 * 9 + p) << 8] +
                  src[(size_t)(2 * 9 + p) << 8] + src[(size_t)(3 * 9 + p) << 8];
        f9[(g * 64 + cf) * 12 + p] = fmaxf(v * sc1 + sh1, 0.f);
      }
    } else {
      for (int p = pg; p < 9; p += 4) f9[(g * 64 + cf) * 12 + p] = 0.f;
    }
  }
  __syncthreads();

  float acc[8];
#pragma unroll
  for (int g = 0; g < 8; ++g) acc[g] = 0.f;
  for (int ci = 0; ci < 64; ++ci) {
    const float* wr = w2n + (size_t)(zb + ci) * 2304 + t;
    float w9[9];
#pragma unroll
    for (int k = 0; k < 9; ++k) w9[k] = wr[k * 256];
#pragma unroll
    for (int g = 0; g < 8; ++g) {
      const float4* fp = (const float4*)(f9 + (g * 64 + ci) * 12);
      float4 f0 = fp[0], f1 = fp[1], f2 = fp[2];
      acc[g] += w9[0] * f0.x;
      acc[g] += w9[1] * f0.y;
      acc[g] += w9[2] * f0.z;
      acc[g] += w9[3] * f0.w;
      acc[g] += w9[4] * f1.x;
      acc[g] += w9[5] * f1.y;
      acc[g] += w9[6] * f1.z;
      acc[g] += w9[7] * f1.w;
      acc[g] += w9[8] * f2.x;
    }
  }
#pragma unroll
  for (int g = 0; g < 8; ++g) {
    const int c = cbase + g;
    if (c < n)
      acc2[((((size_t)(b * CCAP + c)) * 4 + z) << 8) + t] = acc[g];
  }
}

// --- EXACT fp32 rescore, stage C: sum quarters, BN2+ReLU, 1x1 score ---------
// One 64-lane wave per candidate; fixed z-order sum (deterministic).
__global__ __launch_bounds__(256) void rescore_c(const float* __restrict__ acc2,
                                                 const float* __restrict__ bnp,
                                                 const float* __restrict__ b2,
                                                 const int* __restrict__ cnt,
                                                 float* __restrict__ exlog) {
  const int bx = blockIdx.x, b = blockIdx.y, t = threadIdx.x;
  const int lane = t & 63, wid = t >> 6;
  const int n = cnt[b];
  const int c = bx * 4 + wid;
  if (c >= n) return;                  // wave-uniform; no barriers below
  const float* src = acc2 + (((size_t)(b * CCAP + c)) << 10);
  float p = 0.f;
#pragma unroll
  for (int j = 0; j < 4; ++j) {
    const int co = lane + j * 64;
    float v = ((src[co] + src[256 + co]) + src[512 + co]) + src[768 + co];
    p += fmaxf(v * bnp[512 + co] + bnp[768 + co], 0.f) * bnp[1024 + co];
  }
  for (int off = 32; off; off >>= 1) p += __shfl_xor(p, off);
  if (lane == 0) exlog[b * CCAP + c] = p + b2[0];
}

// --- rank-sort exact logits, keep top-100 (jax tie-break: lower idx) --------
__global__ __launch_bounds__(CCAP) void final_topk(const float* __restrict__ exlog,
                                                   const int* __restrict__ cand,
                                                   const int* __restrict__ cnt,
                                                   int* __restrict__ tidx,
                                                   float* __restrict__ tlog) {
  const int b = blockIdx.x, t = threadIdx.x;
  __shared__ float v[CCAP];
  __shared__ int si[CCAP];
  const int n = cnt[b];
  float mv = (t < n) ? exlog[b * CCAP + t] : -3.0e38f;
  int s = (t < n) ? cand[b * CCAP + t] : 0x7FFFFFFF;
  v[t] = mv;
  si[t] = s;
  __syncthreads();
  int rank = 0;
  for (int j = 0; j < CCAP; ++j) {
    float vj = v[j];
    int sj = si[j];
    if (vj > mv || (vj == mv && sj < s)) ++rank;
  }
  if (t < n && rank < 100) {
    tidx[b * 100 + rank] = s;
    tlog[b * 100 + rank] = mv;
  }
}

// --- fused FFN + LN + heads + anchor (fp32 out), one block per query --------
__global__ __launch_bounds__(256) void head_kern(
    const short* __restrict__ featb, const int* __restrict__ tidx,
    const float* __restrict__ tlog, const float* __restrict__ tmpl,
    const float* __restrict__ w1, const float* __restrict__ b1,
    const float* __restrict__ lng, const float* __restrict__ lnb,
    const float* __restrict__ w2, const float* __restrict__ b2,
    const float* __restrict__ zw, const float* __restrict__ zb,
    const float* __restrict__ dmw, const float* __restrict__ dmb,
    const float* __restrict__ yw, const float* __restrict__ yb,
    const float* __restrict__ vw, const float* __restrict__ vb,
    float* __restrict__ out) {
  const int blk = blockIdx.x;  // 400
  const int b = blk / 100, q = blk % 100;
  const int t = threadIdx.x;
  const int lane = t & 63, wid = t >> 6;
  __shared__ float g[256];
  __shared__ float sx[256];
  __shared__ float red[4];
  __shared__ float heads[8];

  const int s = tidx[b * 100 + q];
  const float score = 1.f / (1.f + expf(-tlog[b * 100 + q]));
  const int ys = s >> 7, xs = s & 127;

  g[t] = bf2f(featb[(((size_t)(b * 128 + ys)) * WPITCH + xs + 1) * 256 + t]);
  __syncthreads();

  float x = b1[t];
  {
    const float* wr = w1 + (size_t)t * 256;
    for (int i = 0; i < 256; i += 4) {
      float4 wv = *(const float4*)(wr + i);
      x += g[i] * wv.x + g[i + 1] * wv.y + g[i + 2] * wv.z + g[i + 3] * wv.w;
    }
  }
  float sum = x;
  for (int off = 32; off; off >>= 1) sum += __shfl_xor(sum, off);
  if (lane == 0) red[wid] = sum;
  __syncthreads();
  float mu = (red[0] + red[1] + red[2] + red[3]) * (1.f / 256.f);
  __syncthreads();
  float d = x - mu;
  float q2 = d * d;
  for (int off = 32; off; off >>= 1) q2 += __shfl_xor(q2, off);
  if (lane == 0) red[wid] = q2;
  __syncthreads();
  float var = (red[0] + red[1] + red[2] + red[3]) * (1.f / 256.f);
  float xn = d * (1.f / sqrtf(var + 1e-5f)) * lng[t] + lnb[t];
  xn = fmaxf(xn, 0.f);
  sx[t] = xn;
  __syncthreads();
  float pf = b2[t];
  {
    const float* wr = w2 + (size_t)t * 256;
    for (int i = 0; i < 256; i += 4) {
      float4 wv = *(const float4*)(wr + i);
      pf += sx[i] * wv.x + sx[i + 1] * wv.y + sx[i + 2] * wv.z + sx[i + 3] * wv.w;
    }
  }
  pf *= (1.f + score);
  out[(size_t)(b * 100 + q) * 256 + t] = pf;

  const int k = t >> 5, l = t & 31;
  const float* hw;
  float hb;
  if (k == 0)      { hw = zw;                 hb = zb[0]; }
  else if (k < 4)  { hw = dmw + (k - 1) * 256; hb = dmb[k - 1]; }
  else if (k < 6)  { hw = yw + (k - 4) * 256;  hb = yb[k - 4]; }
  else             { hw = vw + (k - 6) * 256;  hb = vb[k - 6]; }
  float hp = 0.f;
#pragma unroll
  for (int r = 0; r < 8; ++r) {
    int i = l + r * 32;
    hp += g[i] * hw[i];
  }
  for (int off = 16; off; off >>= 1) hp += __shfl_xor(hp, off);
  if (l == 0) heads[k] = hp + hb;
  __syncthreads();

  if (t == 0) {
    const float* pa = tmpl + ((size_t)b * 900 + q) * 11;
    float p[11];
#pragma unroll
    for (int i = 0; i < 11; ++i) p[i] = pa[i];
    float a[11];
    a[0] = ((float)xs + 0.5f) * 0.8f - 51.2f;
    a[1] = ((float)ys + 0.5f) * 0.8f - 51.2f;
    a[2] = p[2] + 0.5f * heads[0];
#pragma unroll
    for (int i = 0; i < 3; ++i)
      a[3 + i] = p[3 + i] + 0.2f * fminf(fmaxf(heads[1 + i], -1.f), 1.f);
    float t0 = tanhf(heads[4]), t1 = tanhf(heads[5]);
    float nrm = fmaxf(sqrtf(t0 * t0 + t1 * t1), 1e-6f);
    a[6] = 0.7f * p[6] + 0.3f * t0 / nrm;
    a[7] = 0.7f * p[7] + 0.3f * t1 / nrm;
    a[8] = p[8] + 0.2f * fminf(fmaxf(heads[6], -2.f), 2.f);
    a[9] = p[9] + 0.2f * fminf(fmaxf(heads[7], -2.f), 2.f);
    a[10] = p[10];
    float* oa = out + 102400 + (size_t)(b * 100 + q) * 11;
#pragma unroll
    for (int i = 0; i < 11; ++i) oa[i] = a[i];
    out[106800 + b * 100 + q] = score;
  }
}

extern "C" void kernel_launch(void* const* d_in, const int* in_sizes, int n_in,
                              void* d_out, int out_size, void* d_ws, size_t ws_size,
                              hipStream_t stream) {
  (void)in_sizes; (void)n_in; (void)out_size; (void)ws_size;
  char* ws = (char*)d_ws;
  short* xn     = (short*)(ws + WSO_XN);
  short* featb  = (short*)(ws + WSO_FEATB);
  short* wp1    = (short*)(ws + WSO_WP1);
  short* wp2    = (short*)(ws + WSO_WP2);
  float* bnp    = (float*)(ws + WSO_BNP);
  float* logits = (float*)(ws + WSO_LOG);
  int*   cand   = (int*)(ws + WSO_CAND);
  int*   cnt    = (int*)(ws + WSO_CNT);
  float* exl    = (float*)(ws + WSO_EXL);
  int*   tidx   = (int*)(ws + WSO_TIDX);
  float* tlog   = (float*)(ws + WSO_TLOG);
  float* w1n    = (float*)(ws + WSO_W1N);
  float* w2n    = (float*)(ws + WSO_W2N);
  float* a1p    = (float*)(ws + WSO_A1P);   // aliases xn (dead after conv1)
  float* acc2   = (float*)(ws + WSO_ACC2);  // also in dead xn region

  const float* bev = (const float*)d_in[0];

  wprep2<<<4608, 256, 0, stream>>>((const float*)d_in[2], (const float*)d_in[7],
                                   wp1, wp2, w1n, w2n);
  smallprep<<<1281, 256, 0, stream>>>(
      (const float*)d_in[3], (const float*)d_in[4], (const float*)d_in[5],
      (const float*)d_in[6], (const float*)d_in[8], (const float*)d_in[9],
      (const float*)d_in[10], (const float*)d_in[11], (const float*)d_in[12],
      (const float*)d_in[13], bnp, xn, featb, logits);
  nchw2nhwc<<<dim3(256, 4, 4), 256, 0, stream>>>(bev, xn);
  conv3x3<0><<<dim3(512, 2), 256, 0, stream>>>(xn, wp1, bnp, bnp + 256,
                                               nullptr, featb, nullptr);
  conv3x3<1><<<dim3(512, 2), 256, 0, stream>>>(featb, wp2, bnp + 512, bnp + 768,
                                               bnp + 1024, nullptr, logits);
  topk_radix<<<4, 1024, 0, stream>>>(logits, cand, cnt);
  // xn is dead from here on; a1part + acc2 reuse its storage.
  rescore_a<<<dim3(CCAP / 4, 4, 8), 256, 0, stream>>>(bev, w1n, cand, cnt, a1p);
  rescore_b<<<dim3(CCAP / 8, 4, 4), 256, 0, stream>>>(a1p, w2n, bnp, cnt, acc2);
  rescore_c<<<dim3(CCAP / 4, 4), 256, 0, stream>>>(acc2, bnp,
                                                   (const float*)d_in[13], cnt,
                                                   exl);
  final_topk<<<4, CCAP, 0, stream>>>(exl, cand, cnt, tidx, tlog);
  head_kern<<<400, 256, 0, stream>>>(
      featb, tidx, tlog, (const float*)d_in[1],
      (const float*)d_in[14], (const float*)d_in[15], (const float*)d_in[16],
      (const float*)d_in[17], (const float*)d_in[18], (const float*)d_in[19],
      (const float*)d_in[20], (const float*)d_in[21], (const float*)d_in[22],
      (const float*)d_in[23], (const float*)d_in[24], (const float*)d_in[25],
      (const float*)d_in[26], (const float*)d_in[27], (float*)d_out);
}

// Round 9
// 563.789 us; speedup vs baseline: 1.3934x; 1.3934x over previous
//
#include <hip/hip_runtime.h>
#include <math.h>

// ---------------------------------------------------------------------------
// LiDARPriorQueryGenerator — MI355X (gfx950). FP32 I/O per reference dtypes.
// wprep2(both weights: bf16 [tap][co][ci] + fp32 [ci][tap][co]) -> smallprep
// (bn-fold, pad-zero, logit-init) -> NHWC bf16 (W padded 130) -> conv1 MFMA
// (single 130-row A tile, dw via ds_read offset) -> featb bf16 -> conv2 MFMA
// + fused 1x1 score -> RADIX-SELECT top>=128 -> EXACT fp32 rescore in THREE
// balanced kernels:
//   rescore_a: grid (cand-quad, b, ci-quarter x co-half) = ~1056 blocks x
//     256 thr (4 waves). LATENCY-bound kernel; lever is resident waves
//     (co-half split halves per-thread work -> 4224 waves). launch_bounds
//     (256,2): r8's (256,4) made the allocator target 64 VGPR and SPILL
//     (WRITE_SIZE 18MB -> 1.03GB, VALUBusy 24%, 3.2x slower); this body
//     compiles to ~104 VGPR at bound 2 (r7-measured), and 4 waves/SIMD
//     still fit (4x104 <= 512) without forcing spills. Each thread: 2 co
//     (co0, co0+128), wave = 1 cand, weight dbuf ping-pong.
//   rescore_b: grid (cand-oct, b, cf-quarter) ~272 blocks; sums 4 split-K
//     partials deterministically, BN1+ReLU -> f9 LDS (24KB), conv2 partial
//     over 64 input channels for 8 cands -> acc2 fp32 partials.
//   rescore_c: one wave per cand; sums 4 cf-quarter partials in fixed order,
//     BN2+ReLU, 1x1 score dot, wave-reduce -> exact logits.
// -> final top-100 -> fused FFN/LN/heads/anchor.
// ---------------------------------------------------------------------------

typedef __attribute__((ext_vector_type(8))) short bf16x8;
typedef __attribute__((ext_vector_type(4))) float f32x4;

#define HW 16384
#define WPITCH 130   // padded width: col 0 and 129 are zero pads
#define CCAP 192     // candidate cap (count(key>=K*) typically 128..~132)
#define PSTR 28      // LDS patch stride (floats) per (cand, ci)
// workspace byte offsets
#define WSO_XN    0ULL           // bf16 NHWC padded input; LATER a1part alias
#define WSO_FEATB 34078720ULL    // bf16 NHWC padded feat   (34,078,720)
#define WSO_WP1   68157440ULL    // bf16 [9][256][256] shared_w
#define WSO_WP2   69337088ULL    // bf16 [9][256][256] obj_w1
#define WSO_BNP   70516736ULL    // fp32 scale1,shift1,scale2,shift2,w2f (1280)
#define WSO_LOG   70521856ULL    // fp32 65536 logits
#define WSO_CAND  70784000ULL    // int 4*CCAP
#define WSO_CNT   70787072ULL    // int 4 (+pad)
#define WSO_EXL   70787136ULL    // fp32 4*CCAP
#define WSO_TIDX  70790208ULL    // int 4*100
#define WSO_TLOG  70791808ULL    // fp32 4*100
#define WSO_W1N   70793408ULL    // fp32 [ci][tap][co] shared_w (2,359,296)
#define WSO_W2N   73152704ULL    // fp32 [ci][tap][co] obj_w1   (2,359,296)
#define WSO_A1P   WSO_XN         // fp32 [b][cand][4][9][256] conv1 partials
                                 //   = 28,311,552 B  (xn dead)
#define WSO_ACC2  28311552ULL    // fp32 [b][cand][4][256] conv2 partials
                                 //   = 3,145,728 B; ends 31,457,280 < FEATB

__device__ __forceinline__ float bf2f(short s) {
  return __uint_as_float(((unsigned)(unsigned short)s) << 16);
}
__device__ __forceinline__ short f2bf(float f) {  // RNE
  unsigned u = __float_as_uint(f);
  u += 0x7fffu + ((u >> 16) & 1u);
  return (short)(u >> 16);
}
__device__ __forceinline__ void gll16(const void* g, void* l) {
  __builtin_amdgcn_global_load_lds(
      (const __attribute__((address_space(1))) void*)g,
      (__attribute__((address_space(3))) void*)l, 16, 0, 0);
}

// --- prep: BOTH conv weights in one launch; coalesced read, two writes:
//   wp  bf16 [tap][co][ci]  (MFMA conv)     wn fp32 [ci][tap][co] (rescore)
__global__ void wprep2(const float* __restrict__ s1, const float* __restrict__ s2,
                       short* __restrict__ wp1, short* __restrict__ wp2,
                       float* __restrict__ wn1, float* __restrict__ wn2) {
  int bx = blockIdx.x;  // grid 4608
  const float* src;
  short* wp;
  float* wn;
  if (bx >= 2304) {
    src = s2; wp = wp2; wn = wn2; bx -= 2304;
  } else {
    src = s1; wp = wp1; wn = wn1;
  }
  int i = bx * 256 + threadIdx.x;
  float v = src[i];
  int k = i % 9;
  int r = i / 9;
  int ci = r & 255;
  int co = r >> 8;
  wp[(k * 256 + co) * 256 + ci] = f2bf(v);
  wn[(ci * 9 + k) * 256 + co] = v;
}

// --- prep: padzero (blocks 0..1023) + loginit (1024..1279) + bnfold (1280) --
__global__ void smallprep(const float* g1, const float* b1, const float* m1,
                          const float* v1, const float* g2, const float* b2,
                          const float* m2, const float* v2, const float* w2,
                          const float* ob2, float* __restrict__ bnp,
                          short* __restrict__ xn, short* __restrict__ featb,
                          float* __restrict__ logits) {
  const int blk = blockIdx.x, t = threadIdx.x;
  if (blk < 1024) {
    int i = blk * 256 + t;
    int c = i & 255;
    int r = i >> 8;
    int nh = r >> 1;
    int side = r & 1;
    size_t off = ((size_t)nh * WPITCH + (side ? 129 : 0)) * 256 + c;
    xn[off] = 0;
    featb[off] = 0;
  } else if (blk < 1280) {
    logits[(blk - 1024) * 256 + t] = ob2[0];
  } else {
    float s1 = g1[t] / sqrtf(v1[t] + 1e-5f);
    bnp[t] = s1;
    bnp[256 + t] = b1[t] - m1[t] * s1;
    float s2 = g2[t] / sqrtf(v2[t] + 1e-5f);
    bnp[512 + t] = s2;
    bnp[768 + t] = b2[t] - m2[t] * s2;
    bnp[1024 + t] = w2[t];
  }
}

// --- NCHW f32 -> NHWC bf16 (padded W) ---------------------------------------
__global__ __launch_bounds__(256) void nchw2nhwc(const float* __restrict__ in,
                                                 short* __restrict__ out) {
  __shared__ short tl[64 * 66];
  int n = blockIdx.z, c0 = blockIdx.y * 64, s0 = blockIdx.x * 64;
  int sl = threadIdx.x & 63, cl = threadIdx.x >> 6;
  for (int p = 0; p < 16; ++p) {
    int c = cl + p * 4;
    tl[c * 66 + sl] = f2bf(in[(((size_t)(n * 256 + c0 + c)) << 14) + s0 + sl]);
  }
  __syncthreads();
  int co = threadIdx.x & 63, so = threadIdx.x >> 6;
  for (int p = 0; p < 16; ++p) {
    int S = s0 + so + p * 4;
    int h = S >> 7, w = S & 127;
    out[(((size_t)(n * 128 + h)) * WPITCH + w + 1) * 256 + c0 + co] =
        tl[co * 66 + (so + p * 4)];
  }
}

// --- 3x3 conv + BN + ReLU via MFMA. Single 130-row A tile per (dh,c0)
// window; the dw shift is a ds_read row offset (A staged ONCE, not 3x).
// B: 3 tap tiles. One barrier drain covers 8 gll16 + tail -> 48 MFMA.
template <int OUT_LOGITS>
__global__ __launch_bounds__(256) void conv3x3(const short* __restrict__ inp,
                                               const short* __restrict__ wp,
                                               const float* __restrict__ scale,
                                               const float* __restrict__ shift,
                                               const float* __restrict__ w2f,
                                               short* __restrict__ outb,
                                               float* __restrict__ logits) {
  __shared__ short a_sm[132 * 32];     // rows 0..129 used (130-row tile)
  __shared__ short b_sm[3][128 * 32];
  const int t = threadIdx.x;
  const int wv = t >> 6, lane = t & 63;
  const int l15 = lane & 15, quad = lane >> 4;
  const int tile = blockIdx.x;
  const int img = tile >> 7;
  const int h = tile & 127;
  const int nblk = blockIdx.y;
  const int m0 = (wv & 1) << 6;
  const int n0 = (wv >> 1) << 6;

  f32x4 acc[4][4];
#pragma unroll
  for (int i = 0; i < 4; ++i)
#pragma unroll
    for (int j = 0; j < 4; ++j) {
      acc[i][j][0] = 0.f; acc[i][j][1] = 0.f;
      acc[i][j][2] = 0.f; acc[i][j][3] = 0.f;
    }

  for (int dhi = 0; dhi < 3; ++dhi) {
    const int hy = h + dhi - 1;
    if (hy < 0 || hy > 127) continue;  // block-uniform row-pad skip
    const size_t arow = ((size_t)(img * 128 + hy)) * WPITCH;
    const short* wbase = wp + ((size_t)(dhi * 3 * 256 + nblk * 128)) * 256;

    for (int c0 = 0; c0 < 256; c0 += 32) {
      __syncthreads();
      // stage A: positions [0,128) via 2 gll16 rounds (full-exec)
#pragma unroll
      for (int j = 0; j < 2; ++j) {
        const int seg = (j << 6) + (t >> 2);
        const int cc = t & 3;
        gll16(inp + (arow + seg) * 256 + c0 + cc * 8,
              a_sm + ((size_t)((j << 8) + t)) * 8);
      }
      // positions 128,129: plain dword load + LDS store (exec-mask-safe)
      if (t < 32) {
        const int r = t >> 4, dw = t & 15;
        const int* gsrc = (const int*)(inp + (arow + 128 + r) * 256 + c0) + dw;
        ((int*)a_sm)[(128 + r) * 16 + dw] = *gsrc;
      }
      // stage B: 3 taps of this dh row
#pragma unroll
      for (int dwi = 0; dwi < 3; ++dwi) {
        const short* wtap = wbase + (size_t)dwi * 65536;
#pragma unroll
        for (int j = 0; j < 2; ++j) {
          const int nrow = (j << 6) + (t >> 2);
          const int cc = t & 3;
          gll16(wtap + (size_t)nrow * 256 + c0 + cc * 8,
                b_sm[dwi] + ((size_t)((j << 8) + t)) * 8);
        }
      }
      __syncthreads();  // single drain -> 48 MFMA

#pragma unroll
      for (int dwi = 0; dwi < 3; ++dwi) {
        bf16x8 af[4], bfr[4];
#pragma unroll
        for (int i = 0; i < 4; ++i)
          af[i] = *(const bf16x8*)(a_sm + (dwi + m0 + i * 16 + l15) * 32 + quad * 8);
#pragma unroll
        for (int i = 0; i < 4; ++i)
          bfr[i] = *(const bf16x8*)(b_sm[dwi] + (n0 + i * 16 + l15) * 32 + quad * 8);
#pragma unroll
        for (int i = 0; i < 4; ++i)
#pragma unroll
          for (int j = 0; j < 4; ++j)
            acc[i][j] = __builtin_amdgcn_mfma_f32_16x16x32_bf16(af[i], bfr[j],
                                                                acc[i][j], 0, 0, 0);
      }
    }
  }

  // C/D map: col = lane&15, row = quad*4 + reg
  float sc[4], sh[4], wf[4];
#pragma unroll
  for (int j = 0; j < 4; ++j) {
    const int co = nblk * 128 + n0 + j * 16 + l15;
    sc[j] = scale[co];
    sh[j] = shift[co];
    if (OUT_LOGITS) wf[j] = w2f[co];
  }
  if (OUT_LOGITS) {
    float* lrow = logits + ((size_t)img << 14) + (h << 7);
#pragma unroll
    for (int i = 0; i < 4; ++i) {
#pragma unroll
      for (int r = 0; r < 4; ++r) {
        float part = 0.f;
#pragma unroll
        for (int j = 0; j < 4; ++j) {
          float v = fmaxf(acc[i][j][r] * sc[j] + sh[j], 0.f);
          part += v * wf[j];
        }
        part += __shfl_xor(part, 1);
        part += __shfl_xor(part, 2);
        part += __shfl_xor(part, 4);
        part += __shfl_xor(part, 8);
        if (l15 == 0)
          atomicAdd(&lrow[m0 + i * 16 + quad * 4 + r], part);
      }
    }
  } else {
    const size_t obase = ((size_t)(img * 128 + h)) * WPITCH + 1;
#pragma unroll
    for (int i = 0; i < 4; ++i) {
#pragma unroll
      for (int j = 0; j < 4; ++j) {
        const int co = nblk * 128 + n0 + j * 16 + l15;
#pragma unroll
        for (int r = 0; r < 4; ++r) {
          const int m = m0 + i * 16 + quad * 4 + r;
          float v = fmaxf(acc[i][j][r] * sc[j] + sh[j], 0.f);
          outb[(obase + m) * 256 + co] = f2bf(v);
        }
      }
    }
  }
}

// --- radix-select: all elements with key >= K* (exact rank-128 key) ---------
__global__ __launch_bounds__(1024) void topk_radix(const float* __restrict__ logits,
                                                   int* __restrict__ cand,
                                                   int* __restrict__ cnt_out) {
  __shared__ int hist[2048];
  __shared__ int wsum[16];
  __shared__ unsigned sel_bin;
  __shared__ int sel_above;
  __shared__ int cntr;
  const int b = blockIdx.x, t = threadIdx.x;
  const int lane = t & 63, wid = t >> 6;
  const float* L = logits + (size_t)b * HW;
  const int base = t * 16;
  unsigned kv[16];
#pragma unroll
  for (int i = 0; i < 4; ++i) {
    float4 v = *(const float4*)(L + base + i * 4);
    float f4[4] = {v.x, v.y, v.z, v.w};
#pragma unroll
    for (int j = 0; j < 4; ++j) {
      unsigned u = __float_as_uint(f4[j]);
      kv[i * 4 + j] = u ^ (((unsigned)((int)u >> 31)) | 0x80000000u);
    }
  }
  unsigned prefix = 0, pmask = 0;
  int need = 128;
  const int shifts[3] = {21, 10, 0};
  const int nbs[3] = {2048, 2048, 1024};

  for (int lev = 0; lev < 3; ++lev) {
    const int shift = shifts[lev];
    const int nb = nbs[lev];
    hist[t] = 0;
    hist[t + 1024] = 0;
    __syncthreads();
#pragma unroll
    for (int i = 0; i < 16; ++i)
      if ((kv[i] & pmask) == prefix)
        atomicAdd(&hist[(kv[i] >> shift) & (nb - 1)], 1);
    __syncthreads();
    const int cs = nb >> 10;
    const int bin_hi = nb - 1 - t * cs;
    const int c_hi = hist[bin_hi];
    const int c_lo = (cs == 2) ? hist[bin_hi - 1] : 0;
    const int s = c_hi + c_lo;
    int inc = s;
    for (int off = 1; off < 64; off <<= 1) {
      int nbr = __shfl_up(inc, off);
      if (lane >= off) inc += nbr;
    }
    if (lane == 63) wsum[wid] = inc;
    __syncthreads();
    if (wid == 0) {
      int wv = (lane < 16) ? wsum[lane] : 0;
      for (int off = 1; off < 16; off <<= 1) {
        int nbr = __shfl_up(wv, off);
        if (lane >= off) wv += nbr;
      }
      if (lane < 16) wsum[lane] = wv;
    }
    __syncthreads();
    const int excl = inc - s + (wid ? wsum[wid - 1] : 0);
    if (excl < need && need <= excl + s) {
      if (need <= excl + c_hi) {
        sel_bin = (unsigned)bin_hi;
        sel_above = excl;
      } else {
        sel_bin = (unsigned)(bin_hi - 1);
        sel_above = excl + c_hi;
      }
    }
    __syncthreads();
    prefix |= sel_bin << shift;
    pmask |= ((unsigned)(nb - 1)) << shift;
    need -= sel_above;
    __syncthreads();
  }
  if (t == 0) cntr = 0;
  __syncthreads();
#pragma unroll
  for (int i = 0; i < 16; ++i) {
    if (kv[i] >= prefix) {
      int p = atomicAdd(&cntr, 1);
      if (p < CCAP) cand[b * CCAP + p] = base + i;
    }
  }
  __syncthreads();
  if (t == 0) cnt_out[b] = (cntr < CCAP) ? cntr : CCAP;
}

// --- rescore_a helpers: 18-weight register tile load + one-cand conv step ---
__device__ __forceinline__ void wload2(const float* __restrict__ wr,
                                       float w[2][9]) {
#pragma unroll
  for (int k = 0; k < 9; ++k) {
    w[0][k] = wr[k * 256];
    w[1][k] = wr[k * 256 + 128];
  }
}

__device__ __forceinline__ void conv_step2(const float* __restrict__ pc,
                                           const float w[2][9], float a[2][9]) {
  float xp[28];
  const float4* pr = (const float4*)pc;
#pragma unroll
  for (int q = 0; q < 7; ++q) {
    float4 v = pr[q];
    xp[q * 4 + 0] = v.x; xp[q * 4 + 1] = v.y;
    xp[q * 4 + 2] = v.z; xp[q * 4 + 3] = v.w;
  }
#pragma unroll
  for (int py = 0; py < 3; ++py)
#pragma unroll
    for (int px = 0; px < 3; ++px)
#pragma unroll
      for (int ky = 0; ky < 3; ++ky)
#pragma unroll
        for (int kx = 0; kx < 3; ++kx) {
          const float xv = xp[(py + ky) * 5 + px + kx];
          const int pp = py * 3 + px, kk = ky * 3 + kx;
          a[0][pp] += w[0][kk] * xv;
          a[1][pp] += w[1][kk] * xv;
        }
}

// --- EXACT fp32 rescore, stage A: conv1 partials ----------------------------
// grid (CCAP/4 cand-quads, B, 8 = ci-quarter*2 + co-half), 256 thr (4 waves).
// LATENCY-bound kernel: lever is resident waves. co-half split halves
// per-thread work -> ~1056 blocks, 4224 waves. launch_bounds(256,2): this
// body needs ~104 VGPR (r7-measured); bound 2 lets the allocator have them
// (r8's bound 4 forced 64 VGPR -> 1GB scratch spill traffic, 3.2x slower).
// Thread map: col = t&63, co0 = hf*64+col; thread computes co0 and co0+128;
// wave g = t>>6 owns one cand. Weight dbuf ping-pong. Per-(cand,quarter,co)
// accumulation order unchanged -> bit-identical output.
__global__ __launch_bounds__(256, 2) void rescore_a(
    const float* __restrict__ bev, const float* __restrict__ w1n,
    const int* __restrict__ cand, const int* __restrict__ cnt,
    float* __restrict__ a1part) {
  const int bx = blockIdx.x, b = blockIdx.y, z = blockIdx.z;
  const int q = z >> 1, hf = z & 1;    // ci-quarter, co-half
  const int t = threadIdx.x;
  const int n = cnt[b];
  const int c0 = bx * 4;
  if (c0 >= n) return;                 // block-uniform
  const int nc = (n - c0 < 4) ? (n - c0) : 4;
  const int ci0 = q << 6;
  __shared__ float patch[4 * 64 * PSTR];  // 28,672 B

  // stage zero-padded 5x5 patches for this ci-quarter, up to 4 candidates
  {
    const int TE = nc * 1600;
    int sg[4];
#pragma unroll
    for (int g = 0; g < 4; ++g) {
      int cc = c0 + g;
      sg[g] = cand[b * CCAP + ((cc < n) ? cc : (n - 1))];
    }
#pragma unroll
    for (int k = 0; k < 25; ++k) {
      int e = t + (k << 8);
      if (e < TE) {
        int g = (e >= 3200) ? ((e >= 4800) ? 3 : 2) : ((e >= 1600) ? 1 : 0);
        int rem = e - g * 1600;
        int ci = rem / 25;
        int rj = rem - ci * 25;
        int r = rj / 5;
        int j = rj - r * 5;
        int s = sg[g];
        int hy = (s >> 7) - 2 + r, wx = (s & 127) - 2 + j;
        float v = 0.f;
        if (hy >= 0 && hy < 128 && wx >= 0 && wx < 128)
          v = bev[(((size_t)(b * 256 + ci0 + ci)) << 14) + (hy << 7) + wx];
        patch[(g * 64 + ci) * PSTR + rj] = v;
      } else {
        // keep LDS defined for inactive slots (reads happen, writes skipped)
        int g2z = (e >= 3200) ? ((e >= 4800) ? 3 : 2) : 1;
        int rem = e - g2z * 1600;
        int ci = rem / 25;
        int rj = rem - ci * 25;
        patch[(g2z * 64 + ci) * PSTR + rj] = 0.f;
      }
    }
  }
  __syncthreads();

  const int col = t & 63;
  const int g = t >> 6;                // wave-uniform candidate index
  const int co0 = (hf << 6) + col;     // thread computes co0 and co0+128
  float a[2][9];
#pragma unroll
  for (int h = 0; h < 2; ++h)
#pragma unroll
    for (int p = 0; p < 9; ++p) a[h][p] = 0.f;

  const float* pbase = patch + (g << 6) * PSTR;
  const float* wbase = w1n + (size_t)ci0 * 2304 + co0;

  float wA[2][9], wB[2][9];
  wload2(wbase, wA);                     // ci = 0
  for (int ci = 0; ci < 64; ci += 2) {
    wload2(wbase + (size_t)(ci + 1) * 2304, wB);   // prefetch ci+1
    conv_step2(pbase + ci * PSTR, wA, a);
    if (ci + 2 < 64)
      wload2(wbase + (size_t)(ci + 2) * 2304, wA); // prefetch ci+2
    conv_step2(pbase + (ci + 1) * PSTR, wB, a);
  }

  if (g < nc) {                          // wave-uniform
    const int c = c0 + g;
    float* dst =
        a1part + ((((size_t)(b * CCAP + c) * 4 + q) * 9) << 8) + co0;
#pragma unroll
    for (int p = 0; p < 9; ++p) {
      dst[p << 8] = a[0][p];
      dst[(p << 8) + 128] = a[1][p];
    }
  }
}

// --- EXACT fp32 rescore, stage B: BN1+ReLU -> conv2 cf-quarter partials -----
// grid (CCAP/8, B, 4 cf-quarters), 256 thr, 24KB LDS. 8 candidates share one
// 0.59MB w2n-quarter stream; each block sums the 4 ci-split conv1 partials
// (fixed order), BN1+ReLU into f9, then conv2 partial over its 64 input
// channels -> acc2[b][cand][z][co].
__global__ __launch_bounds__(256) void rescore_b(const float* __restrict__ a1part,
                                                 const float* __restrict__ w2n,
                                                 const float* __restrict__ bnp,
                                                 const int* __restrict__ cnt,
                                                 float* __restrict__ acc2) {
  const int bx = blockIdx.x, b = blockIdx.y, z = blockIdx.z;
  const int t = threadIdx.x;
  const int n = cnt[b];
  const int cbase = bx * 8;
  if (cbase >= n) return;              // block-uniform
  const int zb = z << 6;
  __shared__ float f9[8 * 64 * 12];    // 24,576 B

  const int cf = t & 63;               // local feature channel
  const int pg = t >> 6;               // wave-uniform p-group
  const int cfg = zb + cf;
  const float sc1 = bnp[cfg], sh1 = bnp[256 + cfg];
#pragma unroll
  for (int g = 0; g < 8; ++g) {
    const int c = cbase + g;
    if (c < n) {                       // block-uniform per g
      const float* src =
          a1part + ((((size_t)(b * CCAP + c)) * 36) << 8) + cfg;
      for (int p = pg; p < 9; p += 4) {
        float v = src[(size_t)(0 * 9 + p) << 8] + src[(size_t)(1 * 9 + p) << 8] +
                  src[(size_t)(2 * 9 + p) << 8] + src[(size_t)(3 * 9 + p) << 8];
        f9[(g * 64 + cf) * 12 + p] = fmaxf(v * sc1 + sh1, 0.f);
      }
    } else {
      for (int p = pg; p < 9; p += 4) f9[(g * 64 + cf) * 12 + p] = 0.f;
    }
  }
  __syncthreads();

  float acc[8];
#pragma unroll
  for (int g = 0; g < 8; ++g) acc[g] = 0.f;
  for (int ci = 0; ci < 64; ++ci) {
    const float* wr = w2n + (size_t)(zb + ci) * 2304 + t;
    float w9[9];
#pragma unroll
    for (int k = 0; k < 9; ++k) w9[k] = wr[k * 256];
#pragma unroll
    for (int g = 0; g < 8; ++g) {
      const float4* fp = (const float4*)(f9 + (g * 64 + ci) * 12);
      float4 f0 = fp[0], f1 = fp[1], f2 = fp[2];
      acc[g] += w9[0] * f0.x;
      acc[g] += w9[1] * f0.y;
      acc[g] += w9[2] * f0.z;
      acc[g] += w9[3] * f0.w;
      acc[g] += w9[4] * f1.x;
      acc[g] += w9[5] * f1.y;
      acc[g] += w9[6] * f1.z;
      acc[g] += w9[7] * f1.w;
      acc[g] += w9[8] * f2.x;
    }
  }
#pragma unroll
  for (int g = 0; g < 8; ++g) {
    const int c = cbase + g;
    if (c < n)
      acc2[((((size_t)(b * CCAP + c)) * 4 + z) << 8) + t] = acc[g];
  }
}

// --- EXACT fp32 rescore, stage C: sum quarters, BN2+ReLU, 1x1 score ---------
// One 64-lane wave per candidate; fixed z-order sum (deterministic).
__global__ __launch_bounds__(256) void rescore_c(const float* __restrict__ acc2,
                                                 const float* __restrict__ bnp,
                                                 const float* __restrict__ b2,
                                                 const int* __restrict__ cnt,
                                                 float* __restrict__ exlog) {
  const int bx = blockIdx.x, b = blockIdx.y, t = threadIdx.x;
  const int lane = t & 63, wid = t >> 6;
  const int n = cnt[b];
  const int c = bx * 4 + wid;
  if (c >= n) return;                  // wave-uniform; no barriers below
  const float* src = acc2 + (((size_t)(b * CCAP + c)) << 10);
  float p = 0.f;
#pragma unroll
  for (int j = 0; j < 4; ++j) {
    const int co = lane + j * 64;
    float v = ((src[co] + src[256 + co]) + src[512 + co]) + src[768 + co];
    p += fmaxf(v * bnp[512 + co] + bnp[768 + co], 0.f) * bnp[1024 + co];
  }
  for (int off = 32; off; off >>= 1) p += __shfl_xor(p, off);
  if (lane == 0) exlog[b * CCAP + c] = p + b2[0];
}

// --- rank-sort exact logits, keep top-100 (jax tie-break: lower idx) --------
__global__ __launch_bounds__(CCAP) void final_topk(const float* __restrict__ exlog,
                                                   const int* __restrict__ cand,
                                                   const int* __restrict__ cnt,
                                                   int* __restrict__ tidx,
                                                   float* __restrict__ tlog) {
  const int b = blockIdx.x, t = threadIdx.x;
  __shared__ float v[CCAP];
  __shared__ int si[CCAP];
  const int n = cnt[b];
  float mv = (t < n) ? exlog[b * CCAP + t] : -3.0e38f;
  int s = (t < n) ? cand[b * CCAP + t] : 0x7FFFFFFF;
  v[t] = mv;
  si[t] = s;
  __syncthreads();
  int rank = 0;
  for (int j = 0; j < CCAP; ++j) {
    float vj = v[j];
    int sj = si[j];
    if (vj > mv || (vj == mv && sj < s)) ++rank;
  }
  if (t < n && rank < 100) {
    tidx[b * 100 + rank] = s;
    tlog[b * 100 + rank] = mv;
  }
}

// --- fused FFN + LN + heads + anchor (fp32 out), one block per query --------
__global__ __launch_bounds__(256) void head_kern(
    const short* __restrict__ featb, const int* __restrict__ tidx,
    const float* __restrict__ tlog, const float* __restrict__ tmpl,
    const float* __restrict__ w1, const float* __restrict__ b1,
    const float* __restrict__ lng, const float* __restrict__ lnb,
    const float* __restrict__ w2, const float* __restrict__ b2,
    const float* __restrict__ zw, const float* __restrict__ zb,
    const float* __restrict__ dmw, const float* __restrict__ dmb,
    const float* __restrict__ yw, const float* __restrict__ yb,
    const float* __restrict__ vw, const float* __restrict__ vb,
    float* __restrict__ out) {
  const int blk = blockIdx.x;  // 400
  const int b = blk / 100, q = blk % 100;
  const int t = threadIdx.x;
  const int lane = t & 63, wid = t >> 6;
  __shared__ float g[256];
  __shared__ float sx[256];
  __shared__ float red[4];
  __shared__ float heads[8];

  const int s = tidx[b * 100 + q];
  const float score = 1.f / (1.f + expf(-tlog[b * 100 + q]));
  const int ys = s >> 7, xs = s & 127;

  g[t] = bf2f(featb[(((size_t)(b * 128 + ys)) * WPITCH + xs + 1) * 256 + t]);
  __syncthreads();

  float x = b1[t];
  {
    const float* wr = w1 + (size_t)t * 256;
    for (int i = 0; i < 256; i += 4) {
      float4 wv = *(const float4*)(wr + i);
      x += g[i] * wv.x + g[i + 1] * wv.y + g[i + 2] * wv.z + g[i + 3] * wv.w;
    }
  }
  float sum = x;
  for (int off = 32; off; off >>= 1) sum += __shfl_xor(sum, off);
  if (lane == 0) red[wid] = sum;
  __syncthreads();
  float mu = (red[0] + red[1] + red[2] + red[3]) * (1.f / 256.f);
  __syncthreads();
  float d = x - mu;
  float q2 = d * d;
  for (int off = 32; off; off >>= 1) q2 += __shfl_xor(q2, off);
  if (lane == 0) red[wid] = q2;
  __syncthreads();
  float var = (red[0] + red[1] + red[2] + red[3]) * (1.f / 256.f);
  float xn = d * (1.f / sqrtf(var + 1e-5f)) * lng[t] + lnb[t];
  xn = fmaxf(xn, 0.f);
  sx[t] = xn;
  __syncthreads();
  float pf = b2[t];
  {
    const float* wr = w2 + (size_t)t * 256;
    for (int i = 0; i < 256; i += 4) {
      float4 wv = *(const float4*)(wr + i);
      pf += sx[i] * wv.x + sx[i + 1] * wv.y + sx[i + 2] * wv.z + sx[i + 3] * wv.w;
    }
  }
  pf *= (1.f + score);
  out[(size_t)(b * 100 + q) * 256 + t] = pf;

  const int k = t >> 5, l = t & 31;
  const float* hw;
  float hb;
  if (k == 0)      { hw = zw;                 hb = zb[0]; }
  else if (k < 4)  { hw = dmw + (k - 1) * 256; hb = dmb[k - 1]; }
  else if (k < 6)  { hw = yw + (k - 4) * 256;  hb = yb[k - 4]; }
  else             { hw = vw + (k - 6) * 256;  hb = vb[k - 6]; }
  float hp = 0.f;
#pragma unroll
  for (int r = 0; r < 8; ++r) {
    int i = l + r * 32;
    hp += g[i] * hw[i];
  }
  for (int off = 16; off; off >>= 1) hp += __shfl_xor(hp, off);
  if (l == 0) heads[k] = hp + hb;
  __syncthreads();

  if (t == 0) {
    const float* pa = tmpl + ((size_t)b * 900 + q) * 11;
    float p[11];
#pragma unroll
    for (int i = 0; i < 11; ++i) p[i] = pa[i];
    float a[11];
    a[0] = ((float)xs + 0.5f) * 0.8f - 51.2f;
    a[1] = ((float)ys + 0.5f) * 0.8f - 51.2f;
    a[2] = p[2] + 0.5f * heads[0];
#pragma unroll
    for (int i = 0; i < 3; ++i)
      a[3 + i] = p[3 + i] + 0.2f * fminf(fmaxf(heads[1 + i], -1.f), 1.f);
    float t0 = tanhf(heads[4]), t1 = tanhf(heads[5]);
    float nrm = fmaxf(sqrtf(t0 * t0 + t1 * t1), 1e-6f);
    a[6] = 0.7f * p[6] + 0.3f * t0 / nrm;
    a[7] = 0.7f * p[7] + 0.3f * t1 / nrm;
    a[8] = p[8] + 0.2f * fminf(fmaxf(heads[6], -2.f), 2.f);
    a[9] = p[9] + 0.2f * fminf(fmaxf(heads[7], -2.f), 2.f);
    a[10] = p[10];
    float* oa = out + 102400 + (size_t)(b * 100 + q) * 11;
#pragma unroll
    for (int i = 0; i < 11; ++i) oa[i] = a[i];
    out[106800 + b * 100 + q] = score;
  }
}

extern "C" void kernel_launch(void* const* d_in, const int* in_sizes, int n_in,
                              void* d_out, int out_size, void* d_ws, size_t ws_size,
                              hipStream_t stream) {
  (void)in_sizes; (void)n_in; (void)out_size; (void)ws_size;
  char* ws = (char*)d_ws;
  short* xn     = (short*)(ws + WSO_XN);
  short* featb  = (short*)(ws + WSO_FEATB);
  short* wp1    = (short*)(ws + WSO_WP1);
  short* wp2    = (short*)(ws + WSO_WP2);
  float* bnp    = (float*)(ws + WSO_BNP);
  float* logits = (float*)(ws + WSO_LOG);
  int*   cand   = (int*)(ws + WSO_CAND);
  int*   cnt    = (int*)(ws + WSO_CNT);
  float* exl    = (float*)(ws + WSO_EXL);
  int*   tidx   = (int*)(ws + WSO_TIDX);
  float* tlog   = (float*)(ws + WSO_TLOG);
  float* w1n    = (float*)(ws + WSO_W1N);
  float* w2n    = (float*)(ws + WSO_W2N);
  float* a1p    = (float*)(ws + WSO_A1P);   // aliases xn (dead after conv1)
  float* acc2   = (float*)(ws + WSO_ACC2);  // also in dead xn region

  const float* bev = (const float*)d_in[0];

  wprep2<<<4608, 256, 0, stream>>>((const float*)d_in[2], (const float*)d_in[7],
                                   wp1, wp2, w1n, w2n);
  smallprep<<<1281, 256, 0, stream>>>(
      (const float*)d_in[3], (const float*)d_in[4], (const float*)d_in[5],
      (const float*)d_in[6], (const float*)d_in[8], (const float*)d_in[9],
      (const float*)d_in[10], (const float*)d_in[11], (const float*)d_in[12],
      (const float*)d_in[13], bnp, xn, featb, logits);
  nchw2nhwc<<<dim3(256, 4, 4), 256, 0, stream>>>(bev, xn);
  conv3x3<0><<<dim3(512, 2), 256, 0, stream>>>(xn, wp1, bnp, bnp + 256,
                                               nullptr, featb, nullptr);
  conv3x3<1><<<dim3(512, 2), 256, 0, stream>>>(featb, wp2, bnp + 512, bnp + 768,
                                               bnp + 1024, nullptr, logits);
  topk_radix<<<4, 1024, 0, stream>>>(logits, cand, cnt);
  // xn is dead from here on; a1part + acc2 reuse its storage.
  rescore_a<<<dim3(CCAP / 4, 4, 8), 256, 0, stream>>>(bev, w1n, cand, cnt, a1p);
  rescore_b<<<dim3(CCAP / 8, 4, 4), 256, 0, stream>>>(a1p, w2n, bnp, cnt, acc2);
  rescore_c<<<dim3(CCAP / 4, 4), 256, 0, stream>>>(acc2, bnp,
                                                   (const float*)d_in[13], cnt,
                                                   exl);
  final_topk<<<4, CCAP, 0, stream>>>(exl, cand, cnt, tidx, tlog);
  head_kern<<<400, 256, 0, stream>>>(
      featb, tidx, tlog, (const float*)d_in[1],
      (const float*)d_in[14], (const float*)d_in[15], (const float*)d_in[16],
      (const float*)d_in[17], (const float*)d_in[18], (const float*)d_in[19],
      (const float*)d_in[20], (const float*)d_in[21], (const float*)d_in[22],
      (const float*)d_in[23], (const float*)d_in[24], (const float*)d_in[25],
      (const float*)d_in[26], (const float*)d_in[27], (float*)d_out);
}

// Round 11
// 494.651 us; speedup vs baseline: 1.5882x; 1.1398x over previous
//
#include <hip/hip_runtime.h>
#include <math.h>

// ---------------------------------------------------------------------------
// LiDARPriorQueryGenerator — MI355X (gfx950). FP32 I/O per reference dtypes.
// wprep2(both weights: bf16 [tap][co][ci] + fp32 [ci][tap][co]) -> smallprep
// (bn-fold, pad-zero, logit-init) -> NHWC bf16 (W padded 130) -> conv1 MFMA
// (2-ROW blocks: B-tile staged once per phase feeds 96 MFMA/wave instead of
// 48 — the 1-row version was stage-bound ~2:1) -> featb bf16 -> conv2 MFMA
// + fused 1x1 score -> RADIX-SELECT top>=128 -> EXACT fp32 rescore in THREE
// balanced kernels:
//   rescore_a: r6-measured best (115.4us, VGPR 124): grid (cand-quad, b,
//     ci-quarter), 256 thr; col=t&63 computes 4 co (col+64h), wave g owns
//     one cand; weight dbuf ping-pong; launch_bounds(256,2). r7/r8/r9
//     restructures (2co/2cand, co-half split) all traded overhead for
//     occupancy at par or worse — this config is the measured floor.
//   rescore_b: grid (cand-oct, b, cf-quarter) ~272 blocks; sums 4 split-K
//     partials deterministically, BN1+ReLU -> f9 LDS (24KB), conv2 partial
//     over 64 input channels for 8 cands -> acc2 fp32 partials.
//   rescore_c: one wave per cand; sums 4 cf-quarter partials in fixed order,
//     BN2+ReLU, 1x1 score dot, wave-reduce -> exact logits.
// -> final top-100 -> fused FFN/LN/heads/anchor.
// ---------------------------------------------------------------------------

typedef __attribute__((ext_vector_type(8))) short bf16x8;
typedef __attribute__((ext_vector_type(4))) float f32x4;

#define HW 16384
#define WPITCH 130   // padded width: col 0 and 129 are zero pads
#define CCAP 192     // candidate cap (count(key>=K*) typically 128..~132)
#define PSTR 28      // LDS patch stride (floats) per (cand, ci)
// workspace byte offsets
#define WSO_XN    0ULL           // bf16 NHWC padded input; LATER a1part alias
#define WSO_FEATB 34078720ULL    // bf16 NHWC padded feat   (34,078,720)
#define WSO_WP1   68157440ULL    // bf16 [9][256][256] shared_w
#define WSO_WP2   69337088ULL    // bf16 [9][256][256] obj_w1
#define WSO_BNP   70516736ULL    // fp32 scale1,shift1,scale2,shift2,w2f (1280)
#define WSO_LOG   70521856ULL    // fp32 65536 logits
#define WSO_CAND  70784000ULL    // int 4*CCAP
#define WSO_CNT   70787072ULL    // int 4 (+pad)
#define WSO_EXL   70787136ULL    // fp32 4*CCAP
#define WSO_TIDX  70790208ULL    // int 4*100
#define WSO_TLOG  70791808ULL    // fp32 4*100
#define WSO_W1N   70793408ULL    // fp32 [ci][tap][co] shared_w (2,359,296)
#define WSO_W2N   73152704ULL    // fp32 [ci][tap][co] obj_w1   (2,359,296)
#define WSO_A1P   WSO_XN         // fp32 [b][cand][4][9][256] conv1 partials
                                 //   = 28,311,552 B  (xn dead)
#define WSO_ACC2  28311552ULL    // fp32 [b][cand][4][256] conv2 partials
                                 //   = 3,145,728 B; ends 31,457,280 < FEATB

__device__ __forceinline__ float bf2f(short s) {
  return __uint_as_float(((unsigned)(unsigned short)s) << 16);
}
__device__ __forceinline__ short f2bf(float f) {  // RNE
  unsigned u = __float_as_uint(f);
  u += 0x7fffu + ((u >> 16) & 1u);
  return (short)(u >> 16);
}
__device__ __forceinline__ void gll16(const void* g, void* l) {
  __builtin_amdgcn_global_load_lds(
      (const __attribute__((address_space(1))) void*)g,
      (__attribute__((address_space(3))) void*)l, 16, 0, 0);
}

// --- prep: BOTH conv weights in one launch; coalesced read, two writes:
//   wp  bf16 [tap][co][ci]  (MFMA conv)     wn fp32 [ci][tap][co] (rescore)
__global__ void wprep2(const float* __restrict__ s1, const float* __restrict__ s2,
                       short* __restrict__ wp1, short* __restrict__ wp2,
                       float* __restrict__ wn1, float* __restrict__ wn2) {
  int bx = blockIdx.x;  // grid 4608
  const float* src;
  short* wp;
  float* wn;
  if (bx >= 2304) {
    src = s2; wp = wp2; wn = wn2; bx -= 2304;
  } else {
    src = s1; wp = wp1; wn = wn1;
  }
  int i = bx * 256 + threadIdx.x;
  float v = src[i];
  int k = i % 9;
  int r = i / 9;
  int ci = r & 255;
  int co = r >> 8;
  wp[(k * 256 + co) * 256 + ci] = f2bf(v);
  wn[(ci * 9 + k) * 256 + co] = v;
}

// --- prep: padzero (blocks 0..1023) + loginit (1024..1279) + bnfold (1280) --
__global__ void smallprep(const float* g1, const float* b1, const float* m1,
                          const float* v1, const float* g2, const float* b2,
                          const float* m2, const float* v2, const float* w2,
                          const float* ob2, float* __restrict__ bnp,
                          short* __restrict__ xn, short* __restrict__ featb,
                          float* __restrict__ logits) {
  const int blk = blockIdx.x, t = threadIdx.x;
  if (blk < 1024) {
    int i = blk * 256 + t;
    int c = i & 255;
    int r = i >> 8;
    int nh = r >> 1;
    int side = r & 1;
    size_t off = ((size_t)nh * WPITCH + (side ? 129 : 0)) * 256 + c;
    xn[off] = 0;
    featb[off] = 0;
  } else if (blk < 1280) {
    logits[(blk - 1024) * 256 + t] = ob2[0];
  } else {
    float s1 = g1[t] / sqrtf(v1[t] + 1e-5f);
    bnp[t] = s1;
    bnp[256 + t] = b1[t] - m1[t] * s1;
    float s2 = g2[t] / sqrtf(v2[t] + 1e-5f);
    bnp[512 + t] = s2;
    bnp[768 + t] = b2[t] - m2[t] * s2;
    bnp[1024 + t] = w2[t];
  }
}

// --- NCHW f32 -> NHWC bf16 (padded W) ---------------------------------------
__global__ __launch_bounds__(256) void nchw2nhwc(const float* __restrict__ in,
                                                 short* __restrict__ out) {
  __shared__ short tl[64 * 66];
  int n = blockIdx.z, c0 = blockIdx.y * 64, s0 = blockIdx.x * 64;
  int sl = threadIdx.x & 63, cl = threadIdx.x >> 6;
  for (int p = 0; p < 16; ++p) {
    int c = cl + p * 4;
    tl[c * 66 + sl] = f2bf(in[(((size_t)(n * 256 + c0 + c)) << 14) + s0 + sl]);
  }
  __syncthreads();
  int co = threadIdx.x & 63, so = threadIdx.x >> 6;
  for (int p = 0; p < 16; ++p) {
    int S = s0 + so + p * 4;
    int h = S >> 7, w = S & 127;
    out[(((size_t)(n * 128 + h)) * WPITCH + w + 1) * 256 + c0 + co] =
        tl[co * 66 + (so + p * 4)];
  }
}

// --- 3x3 conv + BN + ReLU via MFMA, TWO output rows per block ---------------
// grid (256 = 4img x 64 rowpairs, 2 nblk), 256 thr, 41.5KB LDS. B tap tiles
// staged once per (dh,c0) feed BOTH rows (96 MFMA/wave/phase vs 48 in the
// 1-row version, which was stage-bound ~2:1: 33KB stage ~520cyc vs 233cyc
// MFMA). Row-pad handled by per-row block-uniform guards; per-element MFMA
// sequence (dh asc, c0 asc, dw asc) identical to 1-row -> bit-identical.
template <int OUT_LOGITS>
__global__ __launch_bounds__(256, 2) void conv3x3(const short* __restrict__ inp,
                                                  const short* __restrict__ wp,
                                                  const float* __restrict__ scale,
                                                  const float* __restrict__ shift,
                                                  const float* __restrict__ w2f,
                                                  short* __restrict__ outb,
                                                  float* __restrict__ logits) {
  __shared__ short a_sm[2][132 * 32];  // per-row 130-position tile
  __shared__ short b_sm[3][128 * 32];
  const int t = threadIdx.x;
  const int wv = t >> 6, lane = t & 63;
  const int l15 = lane & 15, quad = lane >> 4;
  const int tile = blockIdx.x;
  const int img = tile >> 6;
  const int h0 = (tile & 63) << 1;     // output rows h0, h0+1
  const int nblk = blockIdx.y;
  const int m0 = (wv & 1) << 6;
  const int n0 = (wv >> 1) << 6;

  f32x4 acc[2][4][4];
#pragma unroll
  for (int r = 0; r < 2; ++r)
#pragma unroll
    for (int i = 0; i < 4; ++i)
#pragma unroll
      for (int j = 0; j < 4; ++j) {
        acc[r][i][j][0] = 0.f; acc[r][i][j][1] = 0.f;
        acc[r][i][j][2] = 0.f; acc[r][i][j][3] = 0.f;
      }

  for (int dhi = 0; dhi < 3; ++dhi) {
    const int hy0 = h0 + dhi - 1;      // input row for output row h0
    const int hy1 = hy0 + 1;           // input row for output row h0+1
    const bool v0 = (hy0 >= 0) && (hy0 <= 127);  // block-uniform
    const bool v1 = (hy1 <= 127);                // hy1 >= 0 always
    const size_t arow0 = ((size_t)(img * 128 + hy0)) * WPITCH;
    const size_t arow1 = ((size_t)(img * 128 + hy1)) * WPITCH;
    const short* wbase = wp + ((size_t)(dhi * 3 * 256 + nblk * 128)) * 256;

    for (int c0 = 0; c0 < 256; c0 += 32) {
      __syncthreads();
      // stage A rows (block-uniform guards; positions [0,128) via gll16)
      if (v0) {
#pragma unroll
        for (int j = 0; j < 2; ++j) {
          const int seg = (j << 6) + (t >> 2);
          const int cc = t & 3;
          gll16(inp + (arow0 + seg) * 256 + c0 + cc * 8,
                a_sm[0] + ((size_t)((j << 8) + t)) * 8);
        }
      }
      if (v1) {
#pragma unroll
        for (int j = 0; j < 2; ++j) {
          const int seg = (j << 6) + (t >> 2);
          const int cc = t & 3;
          gll16(inp + (arow1 + seg) * 256 + c0 + cc * 8,
                a_sm[1] + ((size_t)((j << 8) + t)) * 8);
        }
      }
      // positions 128,129 of each row: plain dword load + LDS store
      if (t < 64) {
        const int row = t >> 5;
        const bool vr = row ? v1 : v0;
        if (vr) {
          const size_t ar = row ? arow1 : arow0;
          const int rem = t & 31;
          const int r2 = rem >> 4, dw = rem & 15;
          const int* gsrc = (const int*)(inp + (ar + 128 + r2) * 256 + c0) + dw;
          ((int*)a_sm[row])[(128 + r2) * 16 + dw] = *gsrc;
        }
      }
      // stage B: 3 taps of this dh row (shared by both output rows)
#pragma unroll
      for (int dwi = 0; dwi < 3; ++dwi) {
        const short* wtap = wbase + (size_t)dwi * 65536;
#pragma unroll
        for (int j = 0; j < 2; ++j) {
          const int nrow = (j << 6) + (t >> 2);
          const int cc = t & 3;
          gll16(wtap + (size_t)nrow * 256 + c0 + cc * 8,
                b_sm[dwi] + ((size_t)((j << 8) + t)) * 8);
        }
      }
      __syncthreads();  // single drain -> up to 2 x 48 MFMA

#pragma unroll
      for (int dwi = 0; dwi < 3; ++dwi) {
        bf16x8 bfr[4];
#pragma unroll
        for (int i = 0; i < 4; ++i)
          bfr[i] = *(const bf16x8*)(b_sm[dwi] + (n0 + i * 16 + l15) * 32 + quad * 8);
        if (v0) {
          bf16x8 af[4];
#pragma unroll
          for (int i = 0; i < 4; ++i)
            af[i] = *(const bf16x8*)(a_sm[0] + (dwi + m0 + i * 16 + l15) * 32 + quad * 8);
#pragma unroll
          for (int i = 0; i < 4; ++i)
#pragma unroll
            for (int j = 0; j < 4; ++j)
              acc[0][i][j] = __builtin_amdgcn_mfma_f32_16x16x32_bf16(
                  af[i], bfr[j], acc[0][i][j], 0, 0, 0);
        }
        if (v1) {
          bf16x8 af[4];
#pragma unroll
          for (int i = 0; i < 4; ++i)
            af[i] = *(const bf16x8*)(a_sm[1] + (dwi + m0 + i * 16 + l15) * 32 + quad * 8);
#pragma unroll
          for (int i = 0; i < 4; ++i)
#pragma unroll
            for (int j = 0; j < 4; ++j)
              acc[1][i][j] = __builtin_amdgcn_mfma_f32_16x16x32_bf16(
                  af[i], bfr[j], acc[1][i][j], 0, 0, 0);
        }
      }
    }
  }

  // C/D map: col = lane&15, row = quad*4 + reg
  float sc[4], sh[4], wf[4];
#pragma unroll
  for (int j = 0; j < 4; ++j) {
    const int co = nblk * 128 + n0 + j * 16 + l15;
    sc[j] = scale[co];
    sh[j] = shift[co];
    if (OUT_LOGITS) wf[j] = w2f[co];
  }
#pragma unroll
  for (int r = 0; r < 2; ++r) {
    if (OUT_LOGITS) {
      float* lrow = logits + ((size_t)img << 14) + ((h0 + r) << 7);
#pragma unroll
      for (int i = 0; i < 4; ++i) {
#pragma unroll
        for (int rg = 0; rg < 4; ++rg) {
          float part = 0.f;
#pragma unroll
          for (int j = 0; j < 4; ++j) {
            float v = fmaxf(acc[r][i][j][rg] * sc[j] + sh[j], 0.f);
            part += v * wf[j];
          }
          part += __shfl_xor(part, 1);
          part += __shfl_xor(part, 2);
          part += __shfl_xor(part, 4);
          part += __shfl_xor(part, 8);
          if (l15 == 0)
            atomicAdd(&lrow[m0 + i * 16 + quad * 4 + rg], part);
        }
      }
    } else {
      const size_t obase = ((size_t)(img * 128 + h0 + r)) * WPITCH + 1;
#pragma unroll
      for (int i = 0; i < 4; ++i) {
#pragma unroll
        for (int j = 0; j < 4; ++j) {
          const int co = nblk * 128 + n0 + j * 16 + l15;
#pragma unroll
          for (int rg = 0; rg < 4; ++rg) {
            const int m = m0 + i * 16 + quad * 4 + rg;
            float v = fmaxf(acc[r][i][j][rg] * sc[j] + sh[j], 0.f);
            outb[(obase + m) * 256 + co] = f2bf(v);
          }
        }
      }
    }
  }
}

// --- radix-select: all elements with key >= K* (exact rank-128 key) ---------
__global__ __launch_bounds__(1024) void topk_radix(const float* __restrict__ logits,
                                                   int* __restrict__ cand,
                                                   int* __restrict__ cnt_out) {
  __shared__ int hist[2048];
  __shared__ int wsum[16];
  __shared__ unsigned sel_bin;
  __shared__ int sel_above;
  __shared__ int cntr;
  const int b = blockIdx.x, t = threadIdx.x;
  const int lane = t & 63, wid = t >> 6;
  const float* L = logits + (size_t)b * HW;
  const int base = t * 16;
  unsigned kv[16];
#pragma unroll
  for (int i = 0; i < 4; ++i) {
    float4 v = *(const float4*)(L + base + i * 4);
    float f4[4] = {v.x, v.y, v.z, v.w};
#pragma unroll
    for (int j = 0; j < 4; ++j) {
      unsigned u = __float_as_uint(f4[j]);
      kv[i * 4 + j] = u ^ (((unsigned)((int)u >> 31)) | 0x80000000u);
    }
  }
  unsigned prefix = 0, pmask = 0;
  int need = 128;
  const int shifts[3] = {21, 10, 0};
  const int nbs[3] = {2048, 2048, 1024};

  for (int lev = 0; lev < 3; ++lev) {
    const int shift = shifts[lev];
    const int nb = nbs[lev];
    hist[t] = 0;
    hist[t + 1024] = 0;
    __syncthreads();
#pragma unroll
    for (int i = 0; i < 16; ++i)
      if ((kv[i] & pmask) == prefix)
        atomicAdd(&hist[(kv[i] >> shift) & (nb - 1)], 1);
    __syncthreads();
    const int cs = nb >> 10;
    const int bin_hi = nb - 1 - t * cs;
    const int c_hi = hist[bin_hi];
    const int c_lo = (cs == 2) ? hist[bin_hi - 1] : 0;
    const int s = c_hi + c_lo;
    int inc = s;
    for (int off = 1; off < 64; off <<= 1) {
      int nbr = __shfl_up(inc, off);
      if (lane >= off) inc += nbr;
    }
    if (lane == 63) wsum[wid] = inc;
    __syncthreads();
    if (wid == 0) {
      int wv = (lane < 16) ? wsum[lane] : 0;
      for (int off = 1; off < 16; off <<= 1) {
        int nbr = __shfl_up(wv, off);
        if (lane >= off) wv += nbr;
      }
      if (lane < 16) wsum[lane] = wv;
    }
    __syncthreads();
    const int excl = inc - s + (wid ? wsum[wid - 1] : 0);
    if (excl < need && need <= excl + s) {
      if (need <= excl + c_hi) {
        sel_bin = (unsigned)bin_hi;
        sel_above = excl;
      } else {
        sel_bin = (unsigned)(bin_hi - 1);
        sel_above = excl + c_hi;
      }
    }
    __syncthreads();
    prefix |= sel_bin << shift;
    pmask |= ((unsigned)(nb - 1)) << shift;
    need -= sel_above;
    __syncthreads();
  }
  if (t == 0) cntr = 0;
  __syncthreads();
#pragma unroll
  for (int i = 0; i < 16; ++i) {
    if (kv[i] >= prefix) {
      int p = atomicAdd(&cntr, 1);
      if (p < CCAP) cand[b * CCAP + p] = base + i;
    }
  }
  __syncthreads();
  if (t == 0) cnt_out[b] = (cntr < CCAP) ? cntr : CCAP;
}

// --- rescore_a helpers: 36-weight register tile load + one-ci conv step -----
__device__ __forceinline__ void wload4(const float* __restrict__ wr,
                                       float w[4][9]) {
#pragma unroll
  for (int k = 0; k < 9; ++k)
#pragma unroll
    for (int h = 0; h < 4; ++h)
      w[h][k] = wr[k * 256 + (h << 6)];
}

__device__ __forceinline__ void conv_step(const float* __restrict__ pc,
                                          const float w[4][9], float a[4][9]) {
  float xp[28];
  const float4* pr = (const float4*)pc;
#pragma unroll
  for (int q = 0; q < 7; ++q) {
    float4 v = pr[q];
    xp[q * 4 + 0] = v.x; xp[q * 4 + 1] = v.y;
    xp[q * 4 + 2] = v.z; xp[q * 4 + 3] = v.w;
  }
#pragma unroll
  for (int py = 0; py < 3; ++py)
#pragma unroll
    for (int px = 0; px < 3; ++px)
#pragma unroll
      for (int ky = 0; ky < 3; ++ky)
#pragma unroll
        for (int kx = 0; kx < 3; ++kx) {
          const float xv = xp[(py + ky) * 5 + px + kx];
          const int pp = py * 3 + px, kk = ky * 3 + kx;
          a[0][pp] += w[0][kk] * xv;
          a[1][pp] += w[1][kk] * xv;
          a[2][pp] += w[2][kk] * xv;
          a[3][pp] += w[3][kk] * xv;
        }
}

// --- EXACT fp32 rescore, stage A: conv1 partials (r6-measured best) ---------
// grid (CCAP/4 cand-quads, B, 4 ci-quarters), 256 thr. Thread map: col = t&63
// computes 4 co (col + 64h); wave g = t>>6 owns one cand (patch reads are
// wave-uniform broadcasts). Weight tile double-buffered in registers (wA/wB,
// 2-ci unroll), launch_bounds(256,2) -> 124 VGPR, no spill (r6: 115.4us).
__global__ __launch_bounds__(256, 2) void rescore_a(
    const float* __restrict__ bev, const float* __restrict__ w1n,
    const int* __restrict__ cand, const int* __restrict__ cnt,
    float* __restrict__ a1part) {
  const int bx = blockIdx.x, b = blockIdx.y, z = blockIdx.z;
  const int t = threadIdx.x;
  const int n = cnt[b];
  const int c0 = bx * 4;
  if (c0 >= n) return;                 // block-uniform
  const int nc = (n - c0 < 4) ? (n - c0) : 4;
  const int ci0 = z << 6;
  __shared__ float patch[4 * 64 * PSTR];  // 28,672 B

  // stage zero-padded 5x5 patches for this ci-quarter, up to 4 candidates
  {
    const int TE = nc * 1600;
    int sg[4];
#pragma unroll
    for (int g = 0; g < 4; ++g) {
      int cc = c0 + g;
      sg[g] = cand[b * CCAP + ((cc < n) ? cc : (n - 1))];
    }
#pragma unroll
    for (int k = 0; k < 25; ++k) {
      int e = t + (k << 8);
      if (e < TE) {
        int g = (e >= 3200) ? ((e >= 4800) ? 3 : 2) : ((e >= 1600) ? 1 : 0);
        int rem = e - g * 1600;
        int ci = rem / 25;
        int rj = rem - ci * 25;
        int r = rj / 5;
        int j = rj - r * 5;
        int s = sg[g];
        int hy = (s >> 7) - 2 + r, wx = (s & 127) - 2 + j;
        float v = 0.f;
        if (hy >= 0 && hy < 128 && wx >= 0 && wx < 128)
          v = bev[(((size_t)(b * 256 + ci0 + ci)) << 14) + (hy << 7) + wx];
        patch[(g * 64 + ci) * PSTR + rj] = v;
      } else {
        // keep LDS defined for inactive slots (reads happen, writes skipped)
        int g2z = (e >= 3200) ? ((e >= 4800) ? 3 : 2) : 1;
        int rem = e - g2z * 1600;
        int ci = rem / 25;
        int rj = rem - ci * 25;
        patch[(g2z * 64 + ci) * PSTR + rj] = 0.f;
      }
    }
  }
  __syncthreads();

  const int col = t & 63;    // thread computes co = col + 64h, h = 0..3
  const int g = t >> 6;      // wave-uniform candidate index within quad
  float a[4][9];
#pragma unroll
  for (int h = 0; h < 4; ++h)
#pragma unroll
    for (int p = 0; p < 9; ++p) a[h][p] = 0.f;

  const float* pbase = patch + (g << 6) * PSTR;
  const float* wbase = w1n + (size_t)ci0 * 2304 + col;

  float wA[4][9], wB[4][9];
  wload4(wbase, wA);                     // ci = 0
  for (int ci = 0; ci < 64; ci += 2) {
    wload4(wbase + (size_t)(ci + 1) * 2304, wB);   // prefetch ci+1
    conv_step(pbase + ci * PSTR, wA, a);
    if (ci + 2 < 64)
      wload4(wbase + (size_t)(ci + 2) * 2304, wA); // prefetch ci+2
    conv_step(pbase + (ci + 1) * PSTR, wB, a);
  }

  if (g < nc) {                          // wave-uniform
    const int c = c0 + g;
    float* dst =
        a1part + ((((size_t)(b * CCAP + c) * 4 + z) * 9) << 8) + col;
#pragma unroll
    for (int p = 0; p < 9; ++p)
#pragma unroll
      for (int h = 0; h < 4; ++h)
        dst[(p << 8) + (h << 6)] = a[h][p];
  }
}

// --- EXACT fp32 rescore, stage B: BN1+ReLU -> conv2 cf-quarter partials -----
// grid (CCAP/8, B, 4 cf-quarters), 256 thr, 24KB LDS. 8 candidates share one
// 0.59MB w2n-quarter stream; each block sums the 4 ci-split conv1 partials
// (fixed order), BN1+ReLU into f9, then conv2 partial over its 64 input
// channels -> acc2[b][cand][z][co].
__global__ __launch_bounds__(256) void rescore_b(const float* __restrict__ a1part,
                                                 const float* __restrict__ w2n,
                                                 const float* __restrict__ bnp,
                                                 const int* __restrict__ cnt,
                                                 float* __restrict__ acc2) {
  const int bx = blockIdx.x, b = blockIdx.y, z = blockIdx.z;
  const int t = threadIdx.x;
  const int n = cnt[b];
  const int cbase = bx * 8;
  if (cbase >= n) return;              // block-uniform
  const int zb = z << 6;
  __shared__ float f9[8 * 64 * 12];    // 24,576 B

  const int cf = t & 63;               // local feature channel
  const int pg = t >> 6;               // wave-uniform p-group
  const int cfg = zb + cf;
  const float sc1 = bnp[cfg], sh1 = bnp[256 + cfg];
#pragma unroll
  for (int g = 0; g < 8; ++g) {
    const int c = cbase + g;
    if (c < n) {                       // block-uniform per g
      const float* src =
          a1part + ((((size_t)(b * CCAP + c)) * 36) << 8) + cfg;
      for (int p = pg; p < 9; p += 4) {
        float v = src[(size_t)(0 * 9 + p) << 8] + src[(size_t)(1 * 9 + p) << 8] +
                  src[(size_t)(2 * 9 + p) << 8] + src[(size_t)(3 * 9 + p) << 8];
        f9[(g * 64 + cf) * 12 + p] = fmaxf(v * sc1 + sh1, 0.f);
      }
    } else {
      for (int p = pg; p < 9; p += 4) f9[(g * 64 + cf) * 12 + p] = 0.f;
    }
  }
  __syncthreads();

  float acc[8];
#pragma unroll
  for (int g = 0; g < 8; ++g) acc[g] = 0.f;
  for (int ci = 0; ci < 64; ++ci) {
    const float* wr = w2n + (size_t)(zb + ci) * 2304 + t;
    float w9[9];
#pragma unroll
    for (int k = 0; k < 9; ++k) w9[k] = wr[k * 256];
#pragma unroll
    for (int g = 0; g < 8; ++g) {
      const float4* fp = (const float4*)(f9 + (g * 64 + ci) * 12);
      float4 f0 = fp[0], f1 = fp[1], f2 = fp[2];
      acc[g] += w9[0] * f0.x;
      acc[g] += w9[1] * f0.y;
      acc[g] += w9[2] * f0.z;
      acc[g] += w9[3] * f0.w;
      acc[g] += w9[4] * f1.x;
      acc[g] += w9[5] * f1.y;
      acc[g] += w9[6] * f1.z;
      acc[g] += w9[7] * f1.w;
      acc[g] += w9[8] * f2.x;
    }
  }
#pragma unroll
  for (int g = 0; g < 8; ++g) {
    const int c = cbase + g;
    if (c < n)
      acc2[((((size_t)(b * CCAP + c)) * 4 + z) << 8) + t] = acc[g];
  }
}

// --- EXACT fp32 rescore, stage C: sum quarters, BN2+ReLU, 1x1 score ---------
// One 64-lane wave per candidate; fixed z-order sum (deterministic).
__global__ __launch_bounds__(256) void rescore_c(const float* __restrict__ acc2,
                                                 const float* __restrict__ bnp,
                                                 const float* __restrict__ b2,
                                                 const int* __restrict__ cnt,
                                                 float* __restrict__ exlog) {
  const int bx = blockIdx.x, b = blockIdx.y, t = threadIdx.x;
  const int lane = t & 63, wid = t >> 6;
  const int n = cnt[b];
  const int c = bx * 4 + wid;
  if (c >= n) return;                  // wave-uniform; no barriers below
  const float* src = acc2 + (((size_t)(b * CCAP + c)) << 10);
  float p = 0.f;
#pragma unroll
  for (int j = 0; j < 4; ++j) {
    const int co = lane + j * 64;
    float v = ((src[co] + src[256 + co]) + src[512 + co]) + src[768 + co];
    p += fmaxf(v * bnp[512 + co] + bnp[768 + co], 0.f) * bnp[1024 + co];
  }
  for (int off = 32; off; off >>= 1) p += __shfl_xor(p, off);
  if (lane == 0) exlog[b * CCAP + c] = p + b2[0];
}

// --- rank-sort exact logits, keep top-100 (jax tie-break: lower idx) --------
__global__ __launch_bounds__(CCAP) void final_topk(const float* __restrict__ exlog,
                                                   const int* __restrict__ cand,
                                                   const int* __restrict__ cnt,
                                                   int* __restrict__ tidx,
                                                   float* __restrict__ tlog) {
  const int b = blockIdx.x, t = threadIdx.x;
  __shared__ float v[CCAP];
  __shared__ int si[CCAP];
  const int n = cnt[b];
  float mv = (t < n) ? exlog[b * CCAP + t] : -3.0e38f;
  int s = (t < n) ? cand[b * CCAP + t] : 0x7FFFFFFF;
  v[t] = mv;
  si[t] = s;
  __syncthreads();
  int rank = 0;
  for (int j = 0; j < CCAP; ++j) {
    float vj = v[j];
    int sj = si[j];
    if (vj > mv || (vj == mv && sj < s)) ++rank;
  }
  if (t < n && rank < 100) {
    tidx[b * 100 + rank] = s;
    tlog[b * 100 + rank] = mv;
  }
}

// --- fused FFN + LN + heads + anchor (fp32 out), one block per query --------
__global__ __launch_bounds__(256) void head_kern(
    const short* __restrict__ featb, const int* __restrict__ tidx,
    const float* __restrict__ tlog, const float* __restrict__ tmpl,
    const float* __restrict__ w1, const float* __restrict__ b1,
    const float* __restrict__ lng, const float* __restrict__ lnb,
    const float* __restrict__ w2, const float* __restrict__ b2,
    const float* __restrict__ zw, const float* __restrict__ zb,
    const float* __restrict__ dmw, const float* __restrict__ dmb,
    const float* __restrict__ yw, const float* __restrict__ yb,
    const float* __restrict__ vw, const float* __restrict__ vb,
    float* __restrict__ out) {
  const int blk = blockIdx.x;  // 400
  const int b = blk / 100, q = blk % 100;
  const int t = threadIdx.x;
  const int lane = t & 63, wid = t >> 6;
  __shared__ float g[256];
  __shared__ float sx[256];
  __shared__ float red[4];
  __shared__ float heads[8];

  const int s = tidx[b * 100 + q];
  const float score = 1.f / (1.f + expf(-tlog[b * 100 + q]));
  const int ys = s >> 7, xs = s & 127;

  g[t] = bf2f(featb[(((size_t)(b * 128 + ys)) * WPITCH + xs + 1) * 256 + t]);
  __syncthreads();

  float x = b1[t];
  {
    const float* wr = w1 + (size_t)t * 256;
    for (int i = 0; i < 256; i += 4) {
      float4 wv = *(const float4*)(wr + i);
      x += g[i] * wv.x + g[i + 1] * wv.y + g[i + 2] * wv.z + g[i + 3] * wv.w;
    }
  }
  float sum = x;
  for (int off = 32; off; off >>= 1) sum += __shfl_xor(sum, off);
  if (lane == 0) red[wid] = sum;
  __syncthreads();
  float mu = (red[0] + red[1] + red[2] + red[3]) * (1.f / 256.f);
  __syncthreads();
  float d = x - mu;
  float q2 = d * d;
  for (int off = 32; off; off >>= 1) q2 += __shfl_xor(q2, off);
  if (lane == 0) red[wid] = q2;
  __syncthreads();
  float var = (red[0] + red[1] + red[2] + red[3]) * (1.f / 256.f);
  float xn = d * (1.f / sqrtf(var + 1e-5f)) * lng[t] + lnb[t];
  xn = fmaxf(xn, 0.f);
  sx[t] = xn;
  __syncthreads();
  float pf = b2[t];
  {
    const float* wr = w2 + (size_t)t * 256;
    for (int i = 0; i < 256; i += 4) {
      float4 wv = *(const float4*)(wr + i);
      pf += sx[i] * wv.x + sx[i + 1] * wv.y + sx[i + 2] * wv.z + sx[i + 3] * wv.w;
    }
  }
  pf *= (1.f + score);
  out[(size_t)(b * 100 + q) * 256 + t] = pf;

  const int k = t >> 5, l = t & 31;
  const float* hw;
  float hb;
  if (k == 0)      { hw = zw;                 hb = zb[0]; }
  else if (k < 4)  { hw = dmw + (k - 1) * 256; hb = dmb[k - 1]; }
  else if (k < 6)  { hw = yw + (k - 4) * 256;  hb = yb[k - 4]; }
  else             { hw = vw + (k - 6) * 256;  hb = vb[k - 6]; }
  float hp = 0.f;
#pragma unroll
  for (int r = 0; r < 8; ++r) {
    int i = l + r * 32;
    hp += g[i] * hw[i];
  }
  for (int off = 16; off; off >>= 1) hp += __shfl_xor(hp, off);
  if (l == 0) heads[k] = hp + hb;
  __syncthreads();

  if (t == 0) {
    const float* pa = tmpl + ((size_t)b * 900 + q) * 11;
    float p[11];
#pragma unroll
    for (int i = 0; i < 11; ++i) p[i] = pa[i];
    float a[11];
    a[0] = ((float)xs + 0.5f) * 0.8f - 51.2f;
    a[1] = ((float)ys + 0.5f) * 0.8f - 51.2f;
    a[2] = p[2] + 0.5f * heads[0];
#pragma unroll
    for (int i = 0; i < 3; ++i)
      a[3 + i] = p[3 + i] + 0.2f * fminf(fmaxf(heads[1 + i], -1.f), 1.f);
    float t0 = tanhf(heads[4]), t1 = tanhf(heads[5]);
    float nrm = fmaxf(sqrtf(t0 * t0 + t1 * t1), 1e-6f);
    a[6] = 0.7f * p[6] + 0.3f * t0 / nrm;
    a[7] = 0.7f * p[7] + 0.3f * t1 / nrm;
    a[8] = p[8] + 0.2f * fminf(fmaxf(heads[6], -2.f), 2.f);
    a[9] = p[9] + 0.2f * fminf(fmaxf(heads[7], -2.f), 2.f);
    a[10] = p[10];
    float* oa = out + 102400 + (size_t)(b * 100 + q) * 11;
#pragma unroll
    for (int i = 0; i < 11; ++i) oa[i] = a[i];
    out[106800 + b * 100 + q] = score;
  }
}

extern "C" void kernel_launch(void* const* d_in, const int* in_sizes, int n_in,
                              void* d_out, int out_size, void* d_ws, size_t ws_size,
                              hipStream_t stream) {
  (void)in_sizes; (void)n_in; (void)out_size; (void)ws_size;
  char* ws = (char*)d_ws;
  short* xn     = (short*)(ws + WSO_XN);
  short* featb  = (short*)(ws + WSO_FEATB);
  short* wp1    = (short*)(ws + WSO_WP1);
  short* wp2    = (short*)(ws + WSO_WP2);
  float* bnp    = (float*)(ws + WSO_BNP);
  float* logits = (float*)(ws + WSO_LOG);
  int*   cand   = (int*)(ws + WSO_CAND);
  int*   cnt    = (int*)(ws + WSO_CNT);
  float* exl    = (float*)(ws + WSO_EXL);
  int*   tidx   = (int*)(ws + WSO_TIDX);
  float* tlog   = (float*)(ws + WSO_TLOG);
  float* w1n    = (float*)(ws + WSO_W1N);
  float* w2n    = (float*)(ws + WSO_W2N);
  float* a1p    = (float*)(ws + WSO_A1P);   // aliases xn (dead after conv1)
  float* acc2   = (float*)(ws + WSO_ACC2);  // also in dead xn region

  const float* bev = (const float*)d_in[0];

  wprep2<<<4608, 256, 0, stream>>>((const float*)d_in[2], (const float*)d_in[7],
                                   wp1, wp2, w1n, w2n);
  smallprep<<<1281, 256, 0, stream>>>(
      (const float*)d_in[3], (const float*)d_in[4], (const float*)d_in[5],
      (const float*)d_in[6], (const float*)d_in[8], (const float*)d_in[9],
      (const float*)d_in[10], (const float*)d_in[11], (const float*)d_in[12],
      (const float*)d_in[13], bnp, xn, featb, logits);
  nchw2nhwc<<<dim3(256, 4, 4), 256, 0, stream>>>(bev, xn);
  conv3x3<0><<<dim3(256, 2), 256, 0, stream>>>(xn, wp1, bnp, bnp + 256,
                                               nullptr, featb, nullptr);
  conv3x3<1><<<dim3(256, 2), 256, 0, stream>>>(featb, wp2, bnp + 512, bnp + 768,
                                               bnp + 1024, nullptr, logits);
  topk_radix<<<4, 1024, 0, stream>>>(logits, cand, cnt);
  // xn is dead from here on; a1part + acc2 reuse its storage.
  rescore_a<<<dim3(CCAP / 4, 4, 4), 256, 0, stream>>>(bev, w1n, cand, cnt, a1p);
  rescore_b<<<dim3(CCAP / 8, 4, 4), 256, 0, stream>>>(a1p, w2n, bnp, cnt, acc2);
  rescore_c<<<dim3(CCAP / 4, 4), 256, 0, stream>>>(acc2, bnp,
                                                   (const float*)d_in[13], cnt,
                                                   exl);
  final_topk<<<4, CCAP, 0, stream>>>(exl, cand, cnt, tidx, tlog);
  head_kern<<<400, 256, 0, stream>>>(
      featb, tidx, tlog, (const float*)d_in[1],
      (const float*)d_in[14], (const float*)d_in[15], (const float*)d_in[16],
      (const float*)d_in[17], (const float*)d_in[18], (const float*)d_in[19],
      (const float*)d_in[20], (const float*)d_in[21], (const float*)d_in[22],
      (const float*)d_in[23], (const float*)d_in[24], (const float*)d_in[25],
      (const float*)d_in[26], (const float*)d_in[27], (float*)d_out);
}